// Round 1
// baseline (27512.671 us; speedup 1.0000x reference)
//
#include <hip/hip_runtime.h>
#include <hip/hip_bf16.h>
#include <math.h>

#define DD 768
#define HH 8
#define DHH 96
#define NL 3

static inline int imin(int a, int b) { return a < b ? a : b; }

constexpr int BM = 128, BN = 128, BK = 16;

// C[M, 768] = concat(A0row, A1row)[M, K] @ W[K, 768] + bias
// A row m: part0 = A0[(idx0?idx0[row_off+m]:row_off+m), :768]
//          part1 = A1[(idx1?idx1[row_off+m]:row_off+m), :768]   (if K==1536)
__global__ __launch_bounds__(256)
void gemm_bias(const float* __restrict__ A0, const float* __restrict__ A1,
               const int* __restrict__ idx0, const int* __restrict__ idx1,
               int row_off,
               const float* __restrict__ W, const float* __restrict__ bias,
               float* __restrict__ C, int M, int K)
{
    __shared__ __align__(16) float As[BK][BM];
    __shared__ __align__(16) float Bs[BK][BN];
    const int t = threadIdx.x;
    const int bm = blockIdx.x, bn = blockIdx.y;
    const int tr = t >> 4;        // 0..15
    const int tc = t & 15;        // 0..15
    const int r_l = t >> 2;       // 0..63 (A-load row; +64 for second pass)
    const int kk4 = (t & 3) << 2; // 0,4,8,12
    const int bkk = t >> 5;       // 0..7  (B-load row; +8 for second pass)
    const int bc4 = (t & 31) << 2;// 0..124

    float acc[8][8];
#pragma unroll
    for (int i = 0; i < 8; i++)
#pragma unroll
        for (int j = 0; j < 8; j++) acc[i][j] = 0.f;

    for (int k0 = 0; k0 < K; k0 += BK) {
        const float* Ap; const int* idxp; int kbase;
        if (k0 < DD) { Ap = A0; idxp = idx0; kbase = k0; }
        else         { Ap = A1; idxp = idx1; kbase = k0 - DD; }
        // ---- load A tile (128 x 16) ----
#pragma unroll
        for (int l = 0; l < 2; l++) {
            int r = r_l + l * 64;
            int mrow = bm * BM + r;
            float4 v = make_float4(0.f, 0.f, 0.f, 0.f);
            if (mrow < M) {
                int gm = row_off + mrow;
                int ar = idxp ? idxp[gm] : gm;
                v = *reinterpret_cast<const float4*>(Ap + (size_t)ar * DD + kbase + kk4);
            }
            As[kk4 + 0][r] = v.x; As[kk4 + 1][r] = v.y;
            As[kk4 + 2][r] = v.z; As[kk4 + 3][r] = v.w;
        }
        // ---- load B tile (16 x 128) ----
#pragma unroll
        for (int l = 0; l < 2; l++) {
            int kk = bkk + l * 8;
            float4 v = *reinterpret_cast<const float4*>(
                W + (size_t)(k0 + kk) * DD + bn * BN + bc4);
            *reinterpret_cast<float4*>(&Bs[kk][bc4]) = v;
        }
        __syncthreads();
#pragma unroll
        for (int kk = 0; kk < BK; kk++) {
            float4 a0 = *reinterpret_cast<const float4*>(&As[kk][tr * 4]);
            float4 a1 = *reinterpret_cast<const float4*>(&As[kk][64 + tr * 4]);
            float4 b0 = *reinterpret_cast<const float4*>(&Bs[kk][tc * 4]);
            float4 b1 = *reinterpret_cast<const float4*>(&Bs[kk][64 + tc * 4]);
            float av[8] = {a0.x, a0.y, a0.z, a0.w, a1.x, a1.y, a1.z, a1.w};
            float bv[8] = {b0.x, b0.y, b0.z, b0.w, b1.x, b1.y, b1.z, b1.w};
#pragma unroll
            for (int i = 0; i < 8; i++)
#pragma unroll
                for (int j = 0; j < 8; j++)
                    acc[i][j] = fmaf(av[i], bv[j], acc[i][j]);
        }
        __syncthreads();
    }
    // ---- epilogue: += bias, store ----
#pragma unroll
    for (int ig = 0; ig < 2; ig++)
#pragma unroll
        for (int i = 0; i < 4; i++) {
            int r = ig * 64 + tr * 4 + i;
            int m = bm * BM + r;
            if (m >= M) continue;
#pragma unroll
            for (int jg = 0; jg < 2; jg++) {
                int c = bn * BN + jg * 64 + tc * 4;
                float4 bv = *reinterpret_cast<const float4*>(bias + c);
                float4 o;
                o.x = acc[ig * 4 + i][jg * 4 + 0] + bv.x;
                o.y = acc[ig * 4 + i][jg * 4 + 1] + bv.y;
                o.z = acc[ig * 4 + i][jg * 4 + 2] + bv.z;
                o.w = acc[ig * 4 + i][jg * 4 + 3] + bv.w;
                *reinterpret_cast<float4*>(C + (size_t)m * DD + c) = o;
            }
        }
}

// per-edge: aw[h] = (qh.kh)/sqrt(D); a = exp(lrelu(aw) @ Waw + baw); sc[dst] += a
__global__ __launch_bounds__(256)
void aw_a_kernel(const float* __restrict__ q, const float* __restrict__ k,
                 const float* __restrict__ Waw, const float* __restrict__ baw,
                 const int* __restrict__ dst, int e0, int Mc,
                 float* __restrict__ abuf, float* __restrict__ sc)
{
    int m = blockIdx.x * 256 + threadIdx.x;
    if (m >= Mc) return;
    int e = e0 + m;
    const float* qr = q + (size_t)m * DD;
    const float* kr = k + (size_t)m * DD;
    constexpr float rs = 0.03608439182435161f; // 1/sqrt(768)
    float t[HH];
#pragma unroll
    for (int h = 0; h < HH; h++) {
        float s = 0.f;
        for (int d = h * DHH; d < (h + 1) * DHH; d += 4) {
            float4 qv = *reinterpret_cast<const float4*>(qr + d);
            float4 kv = *reinterpret_cast<const float4*>(kr + d);
            s += qv.x * kv.x + qv.y * kv.y + qv.z * kv.z + qv.w * kv.w;
        }
        float aw = s * rs;
        t[h] = aw > 0.f ? aw : 0.2f * aw;
    }
    int dn = dst[e];
#pragma unroll
    for (int h = 0; h < HH; h++) {
        float z = baw[h];
#pragma unroll
        for (int h2 = 0; h2 < HH; h2++) z = fmaf(t[h2], Waw[h2 * HH + h], z);
        float av = expf(z);
        abuf[(size_t)e * HH + h] = av;
        atomicAdd(&sc[(size_t)dn * HH + h], av);
    }
}

__global__ void att_kernel(float* __restrict__ abuf, const float* __restrict__ sc,
                           const int* __restrict__ dst, int Etot)
{
    int i = blockIdx.x * 256 + threadIdx.x;
    if (i >= Etot * HH) return;
    int e = i >> 3, h = i & 7;
    float s = sc[(size_t)dst[e] * HH + h];
    s = (s == 0.f) ? 1.f : s;
    abuf[i] = abuf[i] / s;
}

__global__ void scale_v_kernel(float* __restrict__ v, const float* __restrict__ abuf,
                               int e0, int Mc)
{
    int i = blockIdx.x * 256 + threadIdx.x; // over Mc*192 float4s
    if (i >= Mc * 192) return;
    int m = i / 192;
    int d4 = (i % 192) * 4;
    int h = d4 / DHH;
    float att = abuf[(size_t)(e0 + m) * HH + h];
    float4* vp = reinterpret_cast<float4*>(v + (size_t)m * DD + d4);
    float4 x = *vp;
    x.x *= att; x.y *= att; x.z *= att; x.w *= att;
    *vp = x;
}

__global__ void scatter_add_kernel(const float* __restrict__ msg, const int* __restrict__ dst,
                                   int e0, int Mc, float* __restrict__ hbuf)
{
    int i = blockIdx.x * 256 + threadIdx.x; // over Mc*192 float4s
    if (i >= Mc * 192) return;
    int m = i / 192;
    int d4 = (i % 192) * 4;
    float4 v = *reinterpret_cast<const float4*>(msg + (size_t)m * DD + d4);
    float* hp = hbuf + (size_t)dst[e0 + m] * DD + d4;
    atomicAdd(hp + 0, v.x); atomicAdd(hp + 1, v.y);
    atomicAdd(hp + 2, v.z); atomicAdd(hp + 3, v.w);
}

// one wave per node: z = lrelu(g) @ Wla2 + bla2 ; la = softmax(z) ; out = x*la0 + h*la1
__global__ __launch_bounds__(256)
void combine_kernel(const float* __restrict__ g, const float* __restrict__ Wla2,
                    const float* __restrict__ bla2, const float* __restrict__ x,
                    const float* __restrict__ h, float* __restrict__ out, int Nn)
{
    int w = threadIdx.x >> 6;
    int lane = threadIdx.x & 63;
    int n = blockIdx.x * 4 + w;
    if (n >= Nn) return;
    float z0 = 0.f, z1 = 0.f;
#pragma unroll
    for (int p = 0; p < 3; p++) {
        int d = p * 256 + lane * 4;
        float4 gv = *reinterpret_cast<const float4*>(g + (size_t)n * DD + d);
        float gvs[4] = {gv.x, gv.y, gv.z, gv.w};
#pragma unroll
        for (int j = 0; j < 4; j++) {
            float tt = gvs[j] > 0.f ? gvs[j] : 0.2f * gvs[j];
            z0 = fmaf(tt, Wla2[(d + j) * 2 + 0], z0);
            z1 = fmaf(tt, Wla2[(d + j) * 2 + 1], z1);
        }
    }
#pragma unroll
    for (int off = 32; off > 0; off >>= 1) {
        z0 += __shfl_xor(z0, off);
        z1 += __shfl_xor(z1, off);
    }
    z0 += bla2[0]; z1 += bla2[1];
    float mx = fmaxf(z0, z1);
    float e0v = expf(z0 - mx), e1v = expf(z1 - mx);
    float inv = 1.f / (e0v + e1v);
    float la0 = e0v * inv, la1 = e1v * inv;
#pragma unroll
    for (int p = 0; p < 3; p++) {
        int d = p * 256 + lane * 4;
        float4 xv = *reinterpret_cast<const float4*>(x + (size_t)n * DD + d);
        float4 hv = *reinterpret_cast<const float4*>(h + (size_t)n * DD + d);
        float4 o;
        o.x = xv.x * la0 + hv.x * la1;
        o.y = xv.y * la0 + hv.y * la1;
        o.z = xv.z * la0 + hv.z * la1;
        o.w = xv.w * la0 + hv.w * la1;
        *reinterpret_cast<float4*>(out + (size_t)n * DD + d) = o;
    }
}

extern "C" void kernel_launch(void* const* d_in, const int* in_sizes, int n_in,
                              void* d_out, int out_size, void* d_ws, size_t ws_size,
                              hipStream_t stream)
{
    const int N = 20000, E = 100000;
    const float* x_in      = (const float*)d_in[0];
    const float* edge_attr = (const float*)d_in[1];
    const float* Wck = (const float*)d_in[2];
    const float* bck = (const float*)d_in[3];
    const float* Wq  = (const float*)d_in[4];
    const float* bq  = (const float*)d_in[5];
    const float* Wv  = (const float*)d_in[6];
    const float* bv  = (const float*)d_in[7];
    const float* Waw = (const float*)d_in[8];
    const float* baw = (const float*)d_in[9];
    const float* Wc  = (const float*)d_in[10];
    const float* bc  = (const float*)d_in[11];
    const float* Wlx = (const float*)d_in[12];
    const float* blx = (const float*)d_in[13];
    const float* Wla1 = (const float*)d_in[14];
    const float* bla1 = (const float*)d_in[15];
    const float* Wla2 = (const float*)d_in[16];
    const float* bla2 = (const float*)d_in[17];
    const int* eidx = (const int*)d_in[18];
    const int* srcp = eidx;       // edge_index[0]
    const int* dstp = eidx + E;   // edge_index[1]

    float* p = (float*)d_ws;
    const size_t NB = (size_t)N * DD;
    float* xA    = p; p += NB;
    float* xB    = p; p += NB;
    float* hbuf  = p; p += NB;
    float* lxbuf = p; p += NB;
    float* gbuf  = p; p += NB;
    float* abuf  = p; p += (size_t)E * HH;
    float* scbuf = p; p += (size_t)N * HH;
    size_t used = (size_t)(p - (float*)d_ws);
    size_t totf = ws_size / sizeof(float);
    size_t availf = totf > used ? totf - used : 0;
    long long ecl = (long long)(availf / (2 * DD));
    int EC = (int)(ecl > (long long)E ? (long long)E : ecl);
    if (EC < 1024) EC = 1024; // below this the workspace is unusable anyway
    float* qc = p; p += (size_t)EC * DD;
    float* kc = p;
    float* vc = qc; float* mc = kc;

    const float* xcur = x_in;
    float* outs[NL] = { xA, xB, (float*)d_out };

    for (int l = 0; l < NL; l++) {
        const float* Wck_l = Wck + (size_t)l * 2 * DD * DD;
        const float* bck_l = bck + (size_t)l * DD;
        const float* Wq_l  = Wq  + (size_t)l * DD * DD;
        const float* bq_l  = bq  + (size_t)l * DD;
        const float* Wv_l  = Wv  + (size_t)l * DD * DD;
        const float* bv_l  = bv  + (size_t)l * DD;
        const float* Waw_l = Waw + (size_t)l * HH * HH;
        const float* baw_l = baw + (size_t)l * HH;
        const float* Wc_l  = Wc  + (size_t)l * DD * DD;
        const float* bc_l  = bc  + (size_t)l * DD;
        const float* Wlx_l = Wlx + (size_t)l * DD * DD;
        const float* blx_l = blx + (size_t)l * DD;
        const float* Wla1_l = Wla1 + (size_t)l * 2 * DD * DD;
        const float* bla1_l = bla1 + (size_t)l * DD;
        const float* Wla2_l = Wla2 + (size_t)l * DD * 2;
        const float* bla2_l = bla2 + (size_t)l * 2;

        // ---- stage 1: a + segment-sum sc ----
        hipMemsetAsync(scbuf, 0, (size_t)N * HH * sizeof(float), stream);
        for (int e0 = 0; e0 < E; e0 += EC) {
            int Mc = imin(EC, E - e0);
            dim3 gg((Mc + BM - 1) / BM, DD / BN);
            gemm_bias<<<gg, 256, 0, stream>>>(xcur, nullptr, dstp, nullptr, e0,
                                              Wq_l, bq_l, qc, Mc, DD);
            gemm_bias<<<gg, 256, 0, stream>>>(edge_attr, xcur, nullptr, srcp, e0,
                                              Wck_l, bck_l, kc, Mc, 2 * DD);
            aw_a_kernel<<<(Mc + 255) / 256, 256, 0, stream>>>(qc, kc, Waw_l, baw_l,
                                                              dstp, e0, Mc, abuf, scbuf);
        }
        att_kernel<<<(E * HH + 255) / 256, 256, 0, stream>>>(abuf, scbuf, dstp, E);

        // ---- stage 2: weighted messages -> h ----
        hipMemsetAsync(hbuf, 0, NB * sizeof(float), stream);
        for (int e0 = 0; e0 < E; e0 += EC) {
            int Mc = imin(EC, E - e0);
            dim3 gg((Mc + BM - 1) / BM, DD / BN);
            gemm_bias<<<gg, 256, 0, stream>>>(xcur, nullptr, srcp, nullptr, e0,
                                              Wv_l, bv_l, vc, Mc, DD);
            scale_v_kernel<<<(Mc * 192 + 255) / 256, 256, 0, stream>>>(vc, abuf, e0, Mc);
            gemm_bias<<<gg, 256, 0, stream>>>(vc, nullptr, nullptr, nullptr, 0,
                                              Wc_l, bc_l, mc, Mc, DD);
            scatter_add_kernel<<<(Mc * 192 + 255) / 256, 256, 0, stream>>>(mc, dstp, e0, Mc, hbuf);
        }

        // ---- stage 3: node update ----
        dim3 gn((N + BM - 1) / BM, DD / BN);
        gemm_bias<<<gn, 256, 0, stream>>>(xcur, nullptr, nullptr, nullptr, 0,
                                          Wlx_l, blx_l, lxbuf, N, DD);
        gemm_bias<<<gn, 256, 0, stream>>>(lxbuf, hbuf, nullptr, nullptr, 0,
                                          Wla1_l, bla1_l, gbuf, N, 2 * DD);
        combine_kernel<<<(N + 3) / 4, 256, 0, stream>>>(gbuf, Wla2_l, bla2_l,
                                                        xcur, hbuf, outs[l], N);
        xcur = outs[l];
    }
}

// Round 2
// 12697.192 us; speedup vs baseline: 2.1668x; 2.1668x over previous
//
#include <hip/hip_runtime.h>
#include <hip/hip_bf16.h>
#include <math.h>

#define DD 768
#define HH 8
#define DHH 96
#define NL 3

typedef __attribute__((ext_vector_type(8))) __bf16 bf16x8;
typedef __attribute__((ext_vector_type(4))) float f32x4;
typedef __attribute__((ext_vector_type(8))) unsigned short u16x8;

static inline int imin(int a, int b) { return a < b ? a : b; }

__device__ inline float b2f(unsigned short u) {
    union { unsigned int v; float f; } x; x.v = ((unsigned int)u) << 16; return x.f;
}
__device__ inline unsigned short f2b_rne(float f) {
    union { float f; unsigned int v; } x; x.f = f;
    unsigned int v = x.v;
    return (unsigned short)((v + 0x7FFFu + ((v >> 16) & 1u)) >> 16);
}

// ---- fp32 -> bf16 bulk convert (8 elems/thread) ----
__global__ void f2b_kernel(const float* __restrict__ in, unsigned short* __restrict__ out, int n8)
{
    int i = blockIdx.x * 256 + threadIdx.x;
    if (i >= n8) return;
    const float4* p = reinterpret_cast<const float4*>(in + (size_t)i * 8);
    float4 a = p[0], b = p[1];
    u16x8 o;
    o[0] = f2b_rne(a.x); o[1] = f2b_rne(a.y); o[2] = f2b_rne(a.z); o[3] = f2b_rne(a.w);
    o[4] = f2b_rne(b.x); o[5] = f2b_rne(b.y); o[6] = f2b_rne(b.z); o[7] = f2b_rne(b.w);
    *reinterpret_cast<u16x8*>(out + (size_t)i * 8) = o;
}

// ---- W [K][768] fp32  ->  Wt [768][K] bf16 ----
__global__ void transpose_w(const float* __restrict__ W, unsigned short* __restrict__ Wt, int K)
{
    __shared__ float tile[32][33];
    int kb = blockIdx.x * 32, nb = blockIdx.y * 32;
    int tx = threadIdx.x & 31, ty = threadIdx.x >> 5;
#pragma unroll
    for (int i = 0; i < 32; i += 8)
        tile[ty + i][tx] = W[(size_t)(kb + ty + i) * DD + nb + tx];
    __syncthreads();
#pragma unroll
    for (int i = 0; i < 32; i += 8)
        Wt[(size_t)(nb + ty + i) * K + kb + tx] = f2b_rne(tile[tx][ty + i]);
}

// ---- MFMA GEMM: C[M,768] = concat(A0,A1)[M,K] @ W[K,768] + bias ----
// A sources are bf16, row stride DD. A row m: idx ? Asrc[idx[row_off+m]] : Asrc[m].
// Wt is [768][K] bf16 (n-major). Output fp32 or bf16.
// LDS tiles [128 rows][64 k] bf16 (128B rows), XOR-swizzled: content[r][s] = src[r][s^(r&7)]
// staged via global_load_lds (linear dest, pre-swizzled source), read with same XOR.
__global__ __launch_bounds__(256)
void gemm_mfma(const unsigned short* __restrict__ A0,
               const unsigned short* __restrict__ A1,
               const int* __restrict__ idx0, const int* __restrict__ idx1,
               int row_off,
               const unsigned short* __restrict__ Wt,
               const float* __restrict__ bias,
               void* __restrict__ Cout, int M, int K, int out_bf16)
{
    __shared__ __align__(16) char smem[32768];
    char* As = smem;
    char* Bs = smem + 16384;
    const int t = threadIdx.x;
    const int l = t & 63;
    const int w = t >> 6;            // wave 0..3
    const int wm = w >> 1, wn = w & 1;
    const int bm = blockIdx.x, bn = blockIdx.y;

    const int srow = t >> 3;         // 0..31 (row within 32-row stripe)
    const int ssrc = ((t & 7) ^ (srow & 7)) * 8;  // swizzled source col (bf16 elems)

    const int lane_r = l & 15;
    const int lane_k = l >> 4;

    f32x4 acc[4][4];
#pragma unroll
    for (int m = 0; m < 4; m++)
#pragma unroll
        for (int n = 0; n < 4; n++) acc[m][n] = (f32x4){0.f, 0.f, 0.f, 0.f};

    for (int k0 = 0; k0 < K; k0 += 64) {
        const unsigned short* Ap; const int* idxp; int kbase;
        if (k0 < DD) { Ap = A0; idxp = idx0; kbase = k0; }
        else         { Ap = A1; idxp = idx1; kbase = k0 - DD; }
#pragma unroll
        for (int i = 0; i < 4; i++) {
            int rt = i * 32 + srow;
            // ---- A tile ----
            int grow = bm * 128 + rt;
            char* ldstA = As + ((i * 32 + w * 8) << 7);
            if (grow < M) {
                int ar = idxp ? idxp[row_off + grow] : grow;
                const unsigned short* g = Ap + (size_t)ar * DD + kbase + ssrc;
                __builtin_amdgcn_global_load_lds(
                    (const __attribute__((address_space(1))) void*)g,
                    (__attribute__((address_space(3))) void*)ldstA, 16, 0, 0);
            }
            // ---- B tile (Wt rows, always in range: grid.y covers 768 exactly) ----
            int gn = bn * 128 + rt;
            const unsigned short* gB = Wt + (size_t)gn * K + k0 + ssrc;
            char* ldstB = Bs + ((i * 32 + w * 8) << 7);
            __builtin_amdgcn_global_load_lds(
                (const __attribute__((address_space(1))) void*)gB,
                (__attribute__((address_space(3))) void*)ldstB, 16, 0, 0);
        }
        __syncthreads();
#pragma unroll
        for (int kk = 0; kk < 2; kk++) {
            bf16x8 af[4], bfr[4];
#pragma unroll
            for (int m = 0; m < 4; m++) {
                int r = wm * 64 + m * 16 + lane_r;
                int slot = (kk * 4 + lane_k) ^ (r & 7);
                af[m] = *reinterpret_cast<const bf16x8*>(As + r * 128 + slot * 16);
            }
#pragma unroll
            for (int n = 0; n < 4; n++) {
                int r = wn * 64 + n * 16 + lane_r;
                int slot = (kk * 4 + lane_k) ^ (r & 7);
                bfr[n] = *reinterpret_cast<const bf16x8*>(Bs + r * 128 + slot * 16);
            }
#pragma unroll
            for (int m = 0; m < 4; m++)
#pragma unroll
                for (int n = 0; n < 4; n++)
                    acc[m][n] = __builtin_amdgcn_mfma_f32_16x16x32_bf16(
                        af[m], bfr[n], acc[m][n], 0, 0, 0);
        }
        __syncthreads();
    }
    // ---- epilogue ----
#pragma unroll
    for (int n = 0; n < 4; n++) {
        int col = bn * 128 + wn * 64 + n * 16 + lane_r;
        float badd = bias ? bias[col] : 0.f;
#pragma unroll
        for (int m = 0; m < 4; m++) {
            int r0 = bm * 128 + wm * 64 + m * 16 + lane_k * 4;
#pragma unroll
            for (int j = 0; j < 4; j++) {
                int r = r0 + j;
                if (r < M) {
                    float val = acc[m][n][j] + badd;
                    if (out_bf16)
                        ((unsigned short*)Cout)[(size_t)r * DD + col] = f2b_rne(val);
                    else
                        ((float*)Cout)[(size_t)r * DD + col] = val;
                }
            }
        }
    }
}

// per-edge: aw[h] = (qh.kh)/sqrt(D); a = exp(lrelu(aw) @ Waw + baw); sc[dst] += a
__global__ __launch_bounds__(256)
void aw_a_kernel(const unsigned short* __restrict__ q, const unsigned short* __restrict__ k,
                 const float* __restrict__ Waw, const float* __restrict__ baw,
                 const int* __restrict__ dst, int e0, int Mc,
                 float* __restrict__ abuf, float* __restrict__ sc)
{
    int m = blockIdx.x * 256 + threadIdx.x;
    if (m >= Mc) return;
    int e = e0 + m;
    const u16x8* qr = reinterpret_cast<const u16x8*>(q + (size_t)m * DD);
    const u16x8* kr = reinterpret_cast<const u16x8*>(k + (size_t)m * DD);
    constexpr float rs = 0.03608439182435161f; // 1/sqrt(768)
    float t[HH];
#pragma unroll
    for (int h = 0; h < HH; h++) {
        float s = 0.f;
#pragma unroll
        for (int c = 0; c < 12; c++) {
            u16x8 qv = qr[h * 12 + c];
            u16x8 kv = kr[h * 12 + c];
#pragma unroll
            for (int j = 0; j < 8; j++) s = fmaf(b2f(qv[j]), b2f(kv[j]), s);
        }
        float aw = s * rs;
        t[h] = aw > 0.f ? aw : 0.2f * aw;
    }
    int dn = dst[e];
#pragma unroll
    for (int h = 0; h < HH; h++) {
        float z = baw[h];
#pragma unroll
        for (int h2 = 0; h2 < HH; h2++) z = fmaf(t[h2], Waw[h2 * HH + h], z);
        float av = expf(z);
        abuf[(size_t)e * HH + h] = av;
        atomicAdd(&sc[(size_t)dn * HH + h], av);
    }
}

__global__ void att_kernel(float* __restrict__ abuf, const float* __restrict__ sc,
                           const int* __restrict__ dst, int Etot)
{
    int i = blockIdx.x * 256 + threadIdx.x;
    if (i >= Etot * HH) return;
    int e = i >> 3, h = i & 7;
    float s = sc[(size_t)dst[e] * HH + h];
    s = (s == 0.f) ? 1.f : s;
    abuf[i] = abuf[i] / s;
}

__global__ void scale_v_kernel(const unsigned short* __restrict__ v, const float* __restrict__ abuf,
                               unsigned short* __restrict__ vb, int e0, int Mc)
{
    int i = blockIdx.x * 256 + threadIdx.x; // over Mc*96 groups of 8
    if (i >= Mc * 96) return;
    int m = i / 96;
    int d8 = (i % 96) * 8;
    int h = d8 / DHH;
    float att = abuf[(size_t)(e0 + m) * HH + h];
    u16x8 x = *reinterpret_cast<const u16x8*>(v + (size_t)m * DD + d8);
    u16x8 o;
#pragma unroll
    for (int j = 0; j < 8; j++) o[j] = f2b_rne(b2f(x[j]) * att);
    *reinterpret_cast<u16x8*>(vb + (size_t)m * DD + d8) = o;
}

__global__ void scatter_add_kernel(const unsigned short* __restrict__ msg, const int* __restrict__ dst,
                                   int e0, int Mc, float* __restrict__ hbuf)
{
    int i = blockIdx.x * 256 + threadIdx.x; // over Mc*96 groups of 8
    if (i >= Mc * 96) return;
    int m = i / 96;
    int d8 = (i % 96) * 8;
    u16x8 v = *reinterpret_cast<const u16x8*>(msg + (size_t)m * DD + d8);
    float* hp = hbuf + (size_t)dst[e0 + m] * DD + d8;
#pragma unroll
    for (int j = 0; j < 8; j++) atomicAdd(hp + j, b2f(v[j]));
}

// one wave per node: z = lrelu(g) @ Wla2 + bla2 ; la = softmax(z) ; out = x*la0 + h*la1
__global__ __launch_bounds__(256)
void combine_kernel(const float* __restrict__ g, const float* __restrict__ Wla2,
                    const float* __restrict__ bla2, const float* __restrict__ x,
                    const float* __restrict__ h, float* __restrict__ out, int Nn)
{
    int w = threadIdx.x >> 6;
    int lane = threadIdx.x & 63;
    int n = blockIdx.x * 4 + w;
    if (n >= Nn) return;
    float z0 = 0.f, z1 = 0.f;
#pragma unroll
    for (int p = 0; p < 3; p++) {
        int d = p * 256 + lane * 4;
        float4 gv = *reinterpret_cast<const float4*>(g + (size_t)n * DD + d);
        float gvs[4] = {gv.x, gv.y, gv.z, gv.w};
#pragma unroll
        for (int j = 0; j < 4; j++) {
            float tt = gvs[j] > 0.f ? gvs[j] : 0.2f * gvs[j];
            z0 = fmaf(tt, Wla2[(d + j) * 2 + 0], z0);
            z1 = fmaf(tt, Wla2[(d + j) * 2 + 1], z1);
        }
    }
#pragma unroll
    for (int off = 32; off > 0; off >>= 1) {
        z0 += __shfl_xor(z0, off);
        z1 += __shfl_xor(z1, off);
    }
    z0 += bla2[0]; z1 += bla2[1];
    float mx = fmaxf(z0, z1);
    float e0v = expf(z0 - mx), e1v = expf(z1 - mx);
    float inv = 1.f / (e0v + e1v);
    float la0 = e0v * inv, la1 = e1v * inv;
#pragma unroll
    for (int p = 0; p < 3; p++) {
        int d = p * 256 + lane * 4;
        float4 xv = *reinterpret_cast<const float4*>(x + (size_t)n * DD + d);
        float4 hv = *reinterpret_cast<const float4*>(h + (size_t)n * DD + d);
        float4 o;
        o.x = xv.x * la0 + hv.x * la1;
        o.y = xv.y * la0 + hv.y * la1;
        o.z = xv.z * la0 + hv.z * la1;
        o.w = xv.w * la0 + hv.w * la1;
        *reinterpret_cast<float4*>(out + (size_t)n * DD + d) = o;
    }
}

extern "C" void kernel_launch(void* const* d_in, const int* in_sizes, int n_in,
                              void* d_out, int out_size, void* d_ws, size_t ws_size,
                              hipStream_t stream)
{
    const int N = 20000, E = 100000;
    const float* x_in      = (const float*)d_in[0];
    const float* edge_attr = (const float*)d_in[1];
    const float* Wck = (const float*)d_in[2];
    const float* bck = (const float*)d_in[3];
    const float* Wq  = (const float*)d_in[4];
    const float* bq  = (const float*)d_in[5];
    const float* Wv  = (const float*)d_in[6];
    const float* bv  = (const float*)d_in[7];
    const float* Waw = (const float*)d_in[8];
    const float* baw = (const float*)d_in[9];
    const float* Wc  = (const float*)d_in[10];
    const float* bc  = (const float*)d_in[11];
    const float* Wlx = (const float*)d_in[12];
    const float* blx = (const float*)d_in[13];
    const float* Wla1 = (const float*)d_in[14];
    const float* bla1 = (const float*)d_in[15];
    const float* Wla2 = (const float*)d_in[16];
    const float* bla2 = (const float*)d_in[17];
    const int* eidx = (const int*)d_in[18];
    const int* srcp = eidx;       // edge_index[0]
    const int* dstp = eidx + E;   // edge_index[1]

    float* p = (float*)d_ws;
    const size_t NB = (size_t)N * DD;   // 15.36M
    float* xA   = p; p += NB;
    float* xB   = p; p += NB;
    float* hbuf = p; p += NB;
    float* gbuf = p; p += NB;
    float* abuf = p; p += (size_t)E * HH;
    float* scbuf = p; p += (size_t)N * HH;
    unsigned short* xb16  = (unsigned short*)p; p += NB / 2;
    unsigned short* hb16  = (unsigned short*)p; p += NB / 2;
    unsigned short* lxb16 = (unsigned short*)p; p += NB / 2;
    // transposed bf16 weights for one layer
    unsigned short* wckt  = (unsigned short*)p;
    unsigned short* wqt   = wckt + (size_t)DD * 2 * DD;
    unsigned short* wvt   = wqt  + (size_t)DD * DD;
    unsigned short* wct   = wvt  + (size_t)DD * DD;
    unsigned short* wlxt  = wct  + (size_t)DD * DD;
    unsigned short* wla1t = wlxt + (size_t)DD * DD;
    p += ((size_t)DD * 2 * DD * 2 + (size_t)DD * DD * 4) / 2;

    size_t used = (size_t)(p - (float*)d_ws);
    size_t totf = ws_size / sizeof(float);
    size_t availf = totf > used ? totf - used : 0;
    long long ecl = (long long)(availf / 1152);   // 3 bf16 chunk buffers of 768 each
    ecl = (ecl / 128) * 128;
    int EC = (int)(ecl > (long long)E ? (long long)E : ecl);
    if (EC < 1024) EC = 1024;
    unsigned short* c0 = (unsigned short*)p;                 // eb16 chunk / v
    unsigned short* c1 = c0 + (size_t)EC * DD;               // q / scaled-v
    unsigned short* c2 = c1 + (size_t)EC * DD;               // k / msg

    const float* xcur = x_in;
    float* outs[NL] = { xA, xB, (float*)d_out };

    for (int l = 0; l < NL; l++) {
        const float* Wck_l = Wck + (size_t)l * 2 * DD * DD;
        const float* bck_l = bck + (size_t)l * DD;
        const float* Wq_l  = Wq  + (size_t)l * DD * DD;
        const float* bq_l  = bq  + (size_t)l * DD;
        const float* Wv_l  = Wv  + (size_t)l * DD * DD;
        const float* bv_l  = bv  + (size_t)l * DD;
        const float* Waw_l = Waw + (size_t)l * HH * HH;
        const float* baw_l = baw + (size_t)l * HH;
        const float* Wc_l  = Wc  + (size_t)l * DD * DD;
        const float* bc_l  = bc  + (size_t)l * DD;
        const float* Wlx_l = Wlx + (size_t)l * DD * DD;
        const float* blx_l = blx + (size_t)l * DD;
        const float* Wla1_l = Wla1 + (size_t)l * 2 * DD * DD;
        const float* bla1_l = bla1 + (size_t)l * DD;
        const float* Wla2_l = Wla2 + (size_t)l * DD * 2;
        const float* bla2_l = bla2 + (size_t)l * 2;

        // ---- per-layer prep: x -> bf16, transpose weights ----
        f2b_kernel<<<(N * 96 + 255) / 256, 256, 0, stream>>>(xcur, xb16, N * 96);
        transpose_w<<<dim3(2 * DD / 32, DD / 32), 256, 0, stream>>>(Wck_l, wckt, 2 * DD);
        transpose_w<<<dim3(DD / 32, DD / 32), 256, 0, stream>>>(Wq_l, wqt, DD);
        transpose_w<<<dim3(DD / 32, DD / 32), 256, 0, stream>>>(Wv_l, wvt, DD);
        transpose_w<<<dim3(DD / 32, DD / 32), 256, 0, stream>>>(Wc_l, wct, DD);
        transpose_w<<<dim3(DD / 32, DD / 32), 256, 0, stream>>>(Wlx_l, wlxt, DD);
        transpose_w<<<dim3(2 * DD / 32, DD / 32), 256, 0, stream>>>(Wla1_l, wla1t, 2 * DD);

        // ---- stage 1: attention coefficients + segment sums ----
        hipMemsetAsync(scbuf, 0, (size_t)N * HH * sizeof(float), stream);
        for (int e0 = 0; e0 < E; e0 += EC) {
            int Mc = imin(EC, E - e0);
            dim3 gg((Mc + 127) / 128, DD / 128);
            f2b_kernel<<<(Mc * 96 + 255) / 256, 256, 0, stream>>>(
                edge_attr + (size_t)e0 * DD, c0, Mc * 96);
            gemm_mfma<<<gg, 256, 0, stream>>>(xb16, nullptr, dstp, nullptr, e0,
                                              wqt, bq_l, c1, Mc, DD, 1);
            gemm_mfma<<<gg, 256, 0, stream>>>(c0, xb16, nullptr, srcp, e0,
                                              wckt, bck_l, c2, Mc, 2 * DD, 1);
            aw_a_kernel<<<(Mc + 255) / 256, 256, 0, stream>>>(c1, c2, Waw_l, baw_l,
                                                              dstp, e0, Mc, abuf, scbuf);
        }
        att_kernel<<<(E * HH + 255) / 256, 256, 0, stream>>>(abuf, scbuf, dstp, E);

        // ---- stage 2: weighted messages -> h ----
        hipMemsetAsync(hbuf, 0, NB * sizeof(float), stream);
        for (int e0 = 0; e0 < E; e0 += EC) {
            int Mc = imin(EC, E - e0);
            dim3 gg((Mc + 127) / 128, DD / 128);
            gemm_mfma<<<gg, 256, 0, stream>>>(xb16, nullptr, srcp, nullptr, e0,
                                              wvt, bv_l, c0, Mc, DD, 1);
            scale_v_kernel<<<(Mc * 96 + 255) / 256, 256, 0, stream>>>(c0, abuf, c1, e0, Mc);
            gemm_mfma<<<gg, 256, 0, stream>>>(c1, nullptr, nullptr, nullptr, 0,
                                              wct, bc_l, c2, Mc, DD, 1);
            scatter_add_kernel<<<(Mc * 96 + 255) / 256, 256, 0, stream>>>(c2, dstp, e0, Mc, hbuf);
        }

        // ---- stage 3: node update ----
        dim3 gn((N + 127) / 128, DD / 128);
        gemm_mfma<<<gn, 256, 0, stream>>>(xb16, nullptr, nullptr, nullptr, 0,
                                          wlxt, blx_l, lxb16, N, DD, 1);
        f2b_kernel<<<(N * 96 + 255) / 256, 256, 0, stream>>>(hbuf, hb16, N * 96);
        gemm_mfma<<<gn, 256, 0, stream>>>(lxb16, hb16, nullptr, nullptr, 0,
                                          wla1t, bla1_l, gbuf, N, 2 * DD, 0);
        combine_kernel<<<(N + 3) / 4, 256, 0, stream>>>(gbuf, Wla2_l, bla2_l,
                                                        xcur, hbuf, outs[l], N);
        xcur = outs[l];
    }
}

// Round 4
// 4586.845 us; speedup vs baseline: 5.9982x; 2.7682x over previous
//
#include <hip/hip_runtime.h>
#include <hip/hip_bf16.h>
#include <math.h>

#define DD 768
#define HH 8
#define DHH 96
#define NL 3
#define NN 20000
#define EE 100000

typedef __attribute__((ext_vector_type(8))) __bf16 bf16x8;
typedef __attribute__((ext_vector_type(4))) float f32x4;
typedef __attribute__((ext_vector_type(8))) unsigned short u16x8;

__host__ __device__ static inline int imin(int a, int b) { return a < b ? a : b; }

__device__ inline float b2f(unsigned short u) {
    union { unsigned int v; float f; } x; x.v = ((unsigned int)u) << 16; return x.f;
}
__device__ inline unsigned short f2b_rne(float f) {
    union { float f; unsigned int v; } x; x.f = f;
    unsigned int v = x.v;
    return (unsigned short)((v + 0x7FFFu + ((v >> 16) & 1u)) >> 16);
}

// ================= CSR build =================
__global__ void deg_kernel(const int* __restrict__ dst, int* __restrict__ cnt)
{
    int i = blockIdx.x * 256 + threadIdx.x;
    if (i < EE) atomicAdd(&cnt[dst[i]], 1);
}

// single-block exclusive scan over NN degrees -> rowptr[NN+1], cursor copy
__global__ __launch_bounds__(256)
void scan_kernel(const int* __restrict__ deg, int* __restrict__ rowptr, int* __restrict__ cursor)
{
    __shared__ int part[256];
    int t = threadIdx.x;
    const int per = (NN + 255) / 256;
    int lo = t * per, hi = imin(NN, lo + per);
    int s = 0;
    for (int i = lo; i < hi; i++) s += deg[i];
    part[t] = s;
    __syncthreads();
    if (t == 0) {
        int acc = 0;
        for (int i = 0; i < 256; i++) { int v = part[i]; part[i] = acc; acc += v; }
        rowptr[NN] = acc;
    }
    __syncthreads();
    int run = part[t];
    for (int i = lo; i < hi; i++) {
        rowptr[i] = run; cursor[i] = run;
        run += deg[i];
    }
}

__global__ void fill_perm(const int* __restrict__ src, const int* __restrict__ dst,
                          int* __restrict__ cursor, int* __restrict__ perm,
                          int* __restrict__ src_s, int* __restrict__ dst_s)
{
    int e = blockIdx.x * 256 + threadIdx.x;
    if (e >= EE) return;
    int d = dst[e];
    int pos = atomicAdd(&cursor[d], 1);
    perm[pos] = e;
    src_s[pos] = src[e];
    dst_s[pos] = d;
}

// ================= conversions =================
__global__ void f2b_kernel(const float* __restrict__ in, unsigned short* __restrict__ out, int n8)
{
    int i = blockIdx.x * 256 + threadIdx.x;
    if (i >= n8) return;
    const float4* p = reinterpret_cast<const float4*>(in + (size_t)i * 8);
    float4 a = p[0], b = p[1];
    u16x8 o;
    o[0] = f2b_rne(a.x); o[1] = f2b_rne(a.y); o[2] = f2b_rne(a.z); o[3] = f2b_rne(a.w);
    o[4] = f2b_rne(b.x); o[5] = f2b_rne(b.y); o[6] = f2b_rne(b.z); o[7] = f2b_rne(b.w);
    *reinterpret_cast<u16x8*>(out + (size_t)i * 8) = o;
}

// gathered fp32 rows -> bf16 chunk rows (edge_attr in perm order)
__global__ void f2b_gather(const float* __restrict__ in, const int* __restrict__ perm,
                           int e0, unsigned short* __restrict__ out, int Mc)
{
    int i = blockIdx.x * 256 + threadIdx.x;
    if (i >= Mc * 96) return;
    int m = i / 96;
    int d8 = (i % 96) * 8;
    int row = perm[e0 + m];
    const float4* p = reinterpret_cast<const float4*>(in + (size_t)row * DD + d8);
    float4 a = p[0], b = p[1];
    u16x8 o;
    o[0] = f2b_rne(a.x); o[1] = f2b_rne(a.y); o[2] = f2b_rne(a.z); o[3] = f2b_rne(a.w);
    o[4] = f2b_rne(b.x); o[5] = f2b_rne(b.y); o[6] = f2b_rne(b.z); o[7] = f2b_rne(b.w);
    *reinterpret_cast<u16x8*>(out + (size_t)m * DD + d8) = o;
}

// ---- W [K][768] fp32 (row stride 768) -> Wt [768][K] bf16 ----
__global__ void transpose_w(const float* __restrict__ W, unsigned short* __restrict__ Wt, int K)
{
    __shared__ float tile[32][33];
    int kb = blockIdx.x * 32, nb = blockIdx.y * 32;
    int tx = threadIdx.x & 31, ty = threadIdx.x >> 5;
#pragma unroll
    for (int i = 0; i < 32; i += 8)
        tile[ty + i][tx] = W[(size_t)(kb + ty + i) * DD + nb + tx];
    __syncthreads();
#pragma unroll
    for (int i = 0; i < 32; i += 8)
        Wt[(size_t)(nb + ty + i) * K + kb + tx] = f2b_rne(tile[tx][ty + i]);
}

// ================= MFMA GEMM =================
// C[M,768] = concat(A0,A1)[M,K] @ W + bias ; Wt [768][K] bf16 n-major.
// LDS [128 r][64 k] bf16, XOR-swizzle via pre-swizzled global source + same XOR on read.
__global__ __launch_bounds__(256)
void gemm_mfma(const unsigned short* __restrict__ A0,
               const unsigned short* __restrict__ A1,
               const int* __restrict__ idx0, const int* __restrict__ idx1,
               int row_off,
               const unsigned short* __restrict__ Wt,
               const float* __restrict__ bias,
               void* __restrict__ Cout, int M, int K, int out_bf16)
{
    __shared__ __align__(16) char smem[32768];
    char* As = smem;
    char* Bs = smem + 16384;
    const int t = threadIdx.x;
    const int l = t & 63;
    const int w = t >> 6;
    const int wm = w >> 1, wn = w & 1;
    const int bm = blockIdx.x, bn = blockIdx.y;

    const int srow = t >> 3;                      // 0..31
    const int ssrc = ((t & 7) ^ (srow & 7)) * 8;  // swizzled source col (bf16)

    const int lane_r = l & 15;
    const int lane_k = l >> 4;

    f32x4 acc[4][4];
#pragma unroll
    for (int m = 0; m < 4; m++)
#pragma unroll
        for (int n = 0; n < 4; n++) acc[m][n] = (f32x4){0.f, 0.f, 0.f, 0.f};

    for (int k0 = 0; k0 < K; k0 += 64) {
        const unsigned short* Ap; const int* idxp; int kbase;
        if (k0 < DD) { Ap = A0; idxp = idx0; kbase = k0; }
        else         { Ap = A1; idxp = idx1; kbase = k0 - DD; }
#pragma unroll
        for (int i = 0; i < 4; i++) {
            int rt = i * 32 + srow;
            int grow = bm * 128 + rt;
            char* ldstA = As + ((i * 32 + w * 8) << 7);
            if (grow < M) {
                int ar = idxp ? idxp[row_off + grow] : grow;
                const unsigned short* g = Ap + (size_t)ar * DD + kbase + ssrc;
                __builtin_amdgcn_global_load_lds(
                    (const __attribute__((address_space(1))) void*)g,
                    (__attribute__((address_space(3))) void*)ldstA, 16, 0, 0);
            }
            int gn = bn * 128 + rt;
            const unsigned short* gB = Wt + (size_t)gn * K + k0 + ssrc;
            char* ldstB = Bs + ((i * 32 + w * 8) << 7);
            __builtin_amdgcn_global_load_lds(
                (const __attribute__((address_space(1))) void*)gB,
                (__attribute__((address_space(3))) void*)ldstB, 16, 0, 0);
        }
        __syncthreads();
#pragma unroll
        for (int kk = 0; kk < 2; kk++) {
            bf16x8 af[4], bfr[4];
#pragma unroll
            for (int m = 0; m < 4; m++) {
                int r = wm * 64 + m * 16 + lane_r;
                int slot = (kk * 4 + lane_k) ^ (r & 7);
                af[m] = *reinterpret_cast<const bf16x8*>(As + r * 128 + slot * 16);
            }
#pragma unroll
            for (int n = 0; n < 4; n++) {
                int r = wn * 64 + n * 16 + lane_r;
                int slot = (kk * 4 + lane_k) ^ (r & 7);
                bfr[n] = *reinterpret_cast<const bf16x8*>(Bs + r * 128 + slot * 16);
            }
#pragma unroll
            for (int m = 0; m < 4; m++)
#pragma unroll
                for (int n = 0; n < 4; n++)
                    acc[m][n] = __builtin_amdgcn_mfma_f32_16x16x32_bf16(
                        af[m], bfr[n], acc[m][n], 0, 0, 0);
        }
        __syncthreads();
    }
#pragma unroll
    for (int n = 0; n < 4; n++) {
        int col = bn * 128 + wn * 64 + n * 16 + lane_r;
        float badd = bias ? bias[col] : 0.f;
#pragma unroll
        for (int m = 0; m < 4; m++) {
            int r0 = bm * 128 + wm * 64 + m * 16 + lane_k * 4;
#pragma unroll
            for (int j = 0; j < 4; j++) {
                int r = r0 + j;
                if (r < M) {
                    float val = acc[m][n][j] + badd;
                    if (out_bf16)
                        ((unsigned short*)Cout)[(size_t)r * DD + col] = f2b_rne(val);
                    else
                        ((float*)Cout)[(size_t)r * DD + col] = val;
                }
            }
        }
    }
}

// ================= edge attention =================
// per sorted-edge j: k = kea[j-e0] + kn[src_s[j]]; aw[h]=(q.k)/sqrt(D);
// a = exp(lrelu(aw)@Waw + baw) -> abuf[j]
__global__ __launch_bounds__(256)
void aw_a_sorted(const unsigned short* __restrict__ kea,
                 const unsigned short* __restrict__ kn,
                 const unsigned short* __restrict__ qn,
                 const float* __restrict__ Waw, const float* __restrict__ baw,
                 const int* __restrict__ src_s, const int* __restrict__ dst_s,
                 int e0, int Mc, float* __restrict__ abuf)
{
    int m = blockIdx.x * 256 + threadIdx.x;
    if (m >= Mc) return;
    int j = e0 + m;
    const u16x8* ke = reinterpret_cast<const u16x8*>(kea + (size_t)m * DD);
    const u16x8* kr = reinterpret_cast<const u16x8*>(kn + (size_t)src_s[j] * DD);
    const u16x8* qr = reinterpret_cast<const u16x8*>(qn + (size_t)dst_s[j] * DD);
    constexpr float rs = 0.03608439182435161f; // 1/sqrt(768)
    float t[HH];
#pragma unroll
    for (int h = 0; h < HH; h++) {
        float s = 0.f;
#pragma unroll
        for (int c = 0; c < 12; c++) {
            u16x8 qv = qr[h * 12 + c];
            u16x8 k1 = ke[h * 12 + c];
            u16x8 k2 = kr[h * 12 + c];
#pragma unroll
            for (int x = 0; x < 8; x++)
                s = fmaf(b2f(qv[x]), b2f(k1[x]) + b2f(k2[x]), s);
        }
        float aw = s * rs;
        t[h] = aw > 0.f ? aw : 0.2f * aw;
    }
#pragma unroll
    for (int h = 0; h < HH; h++) {
        float z = baw[h];
#pragma unroll
        for (int h2 = 0; h2 < HH; h2++) z = fmaf(t[h2], Waw[h2 * HH + h], z);
        abuf[(size_t)j * HH + h] = expf(z);
    }
}

// sc[n][h] = sum over run
__global__ void sc_gather(const float* __restrict__ abuf, const int* __restrict__ rowptr,
                          float* __restrict__ sc)
{
    int i = blockIdx.x * 256 + threadIdx.x;
    if (i >= NN * HH) return;
    int n = i >> 3, h = i & 7;
    int jlo = rowptr[n], jhi = rowptr[n + 1];
    float s = 0.f;
    for (int j = jlo; j < jhi; j++) s += abuf[(size_t)j * HH + h];
    sc[i] = s;
}

__global__ void att_kernel(float* __restrict__ abuf, const float* __restrict__ sc,
                           const int* __restrict__ dst_s)
{
    int i = blockIdx.x * 256 + threadIdx.x;
    if (i >= EE * HH) return;
    int j = i >> 3, h = i & 7;
    float s = sc[(size_t)dst_s[j] * HH + h];
    s = (s == 0.f) ? 1.f : s;
    abuf[i] = abuf[i] / s;
}

// vs[m] = att[e0+m] (*) vn[src_s[e0+m]]
__global__ void vs_kernel(const unsigned short* __restrict__ vn, const float* __restrict__ abuf,
                          const int* __restrict__ src_s, int e0,
                          unsigned short* __restrict__ vs, int Mc)
{
    int i = blockIdx.x * 256 + threadIdx.x;
    if (i >= Mc * 96) return;
    int m = i / 96;
    int d8 = (i % 96) * 8;
    int h = d8 / DHH;
    int j = e0 + m;
    float att = abuf[(size_t)j * HH + h];
    u16x8 x = *reinterpret_cast<const u16x8*>(vn + (size_t)src_s[j] * DD + d8);
    u16x8 o;
#pragma unroll
    for (int c = 0; c < 8; c++) o[c] = f2b_rne(b2f(x[c]) * att);
    *reinterpret_cast<u16x8*>(vs + (size_t)m * DD + d8) = o;
}

// hbuf[n] += sum of msg rows in [max(rowptr[n],e0), min(rowptr[n+1],eHi))
__global__ __launch_bounds__(256)
void h_gather(const unsigned short* __restrict__ msg, const int* __restrict__ rowptr,
              int e0, int eHi, float* __restrict__ hbuf)
{
    int n = blockIdx.x;
    int jlo = rowptr[n], jhi = rowptr[n + 1];
    if (jlo < e0) jlo = e0;
    if (jhi > eHi) jhi = eHi;
    if (jlo >= jhi) return;
    int t = threadIdx.x;
    float a0 = 0.f, a1 = 0.f, a2 = 0.f;
    for (int j = jlo; j < jhi; j++) {
        const unsigned short* r = msg + (size_t)(j - e0) * DD;
        a0 += b2f(r[t]); a1 += b2f(r[t + 256]); a2 += b2f(r[t + 512]);
    }
    float* hp = hbuf + (size_t)n * DD;
    hp[t] += a0; hp[t + 256] += a1; hp[t + 512] += a2;
}

// one wave per node: z = lrelu(g)@Wla2 + bla2 ; la = softmax(z) ; out = x*la0 + h*la1
__global__ __launch_bounds__(256)
void combine_kernel(const unsigned short* __restrict__ g, const float* __restrict__ Wla2,
                    const float* __restrict__ bla2, const float* __restrict__ x,
                    const float* __restrict__ h, float* __restrict__ out, int Nn)
{
    int w = threadIdx.x >> 6;
    int lane = threadIdx.x & 63;
    int n = blockIdx.x * 4 + w;
    if (n >= Nn) return;
    float z0 = 0.f, z1 = 0.f;
#pragma unroll
    for (int p = 0; p < 3; p++) {
        int d = p * 256 + lane * 4;
        const unsigned short* gp = g + (size_t)n * DD + d;
#pragma unroll
        for (int j = 0; j < 4; j++) {
            float gv = b2f(gp[j]);
            float tt = gv > 0.f ? gv : 0.2f * gv;
            z0 = fmaf(tt, Wla2[(d + j) * 2 + 0], z0);
            z1 = fmaf(tt, Wla2[(d + j) * 2 + 1], z1);
        }
    }
#pragma unroll
    for (int off = 32; off > 0; off >>= 1) {
        z0 += __shfl_xor(z0, off);
        z1 += __shfl_xor(z1, off);
    }
    z0 += bla2[0]; z1 += bla2[1];
    float mx = fmaxf(z0, z1);
    float e0v = expf(z0 - mx), e1v = expf(z1 - mx);
    float inv = 1.f / (e0v + e1v);
    float la0 = e0v * inv, la1 = e1v * inv;
#pragma unroll
    for (int p = 0; p < 3; p++) {
        int d = p * 256 + lane * 4;
        float4 xv = *reinterpret_cast<const float4*>(x + (size_t)n * DD + d);
        float4 hv = *reinterpret_cast<const float4*>(h + (size_t)n * DD + d);
        float4 o;
        o.x = xv.x * la0 + hv.x * la1;
        o.y = xv.y * la0 + hv.y * la1;
        o.z = xv.z * la0 + hv.z * la1;
        o.w = xv.w * la0 + hv.w * la1;
        *reinterpret_cast<float4*>(out + (size_t)n * DD + d) = o;
    }
}

extern "C" void kernel_launch(void* const* d_in, const int* in_sizes, int n_in,
                              void* d_out, int out_size, void* d_ws, size_t ws_size,
                              hipStream_t stream)
{
    const int N = NN, E = EE;
    const float* x_in      = (const float*)d_in[0];
    const float* edge_attr = (const float*)d_in[1];
    const float* Wck = (const float*)d_in[2];
    const float* bck = (const float*)d_in[3];
    const float* Wq  = (const float*)d_in[4];
    const float* bq  = (const float*)d_in[5];
    const float* Wv  = (const float*)d_in[6];
    const float* bv  = (const float*)d_in[7];
    const float* Waw = (const float*)d_in[8];
    const float* baw = (const float*)d_in[9];
    const float* Wc  = (const float*)d_in[10];
    const float* bc  = (const float*)d_in[11];
    const float* Wlx = (const float*)d_in[12];
    const float* blx = (const float*)d_in[13];
    const float* Wla1 = (const float*)d_in[14];
    const float* bla1 = (const float*)d_in[15];
    const float* Wla2 = (const float*)d_in[16];
    const float* bla2 = (const float*)d_in[17];
    const int* eidx = (const int*)d_in[18];
    const int* srcp = eidx;       // edge_index[0]
    const int* dstp = eidx + E;   // edge_index[1]

    float* p = (float*)d_ws;
    const size_t NB = (size_t)N * DD;   // 15.36M
    float* xA    = p; p += NB;
    float* xB    = p; p += NB;
    float* hbuf  = p; p += NB;
    float* abuf  = p; p += (size_t)E * HH;
    float* scbuf = p; p += (size_t)N * HH;
    // int region
    int* rowptr = (int*)p;
    int* cursor = rowptr + (N + 1);
    int* perm   = cursor + N;
    int* src_s  = perm + E;
    int* dst_s  = src_s + E;
    p += (size_t)(2 * N + 1 + 3 * E + 63) / 64 * 64;
    // bf16 regions (sized in floats = elems/2)
    unsigned short* xb16  = (unsigned short*)p; p += NB / 2;
    unsigned short* hb16  = (unsigned short*)p; p += NB / 2;
    unsigned short* lxb16 = (unsigned short*)p; p += NB / 2;
    unsigned short* qn16  = (unsigned short*)p; p += NB / 2;  // stage1 q / stage2 vn
    unsigned short* kn16  = (unsigned short*)p; p += NB / 2;  // stage1 kn / stage3 g
    unsigned short* vn16  = qn16;
    unsigned short* gb16  = kn16;
    // transposed bf16 weights
    unsigned short* wqt     = (unsigned short*)p;
    unsigned short* wcktopt = wqt     + (size_t)DD * DD;
    unsigned short* wckbott = wcktopt + (size_t)DD * DD;
    unsigned short* wvt     = wckbott + (size_t)DD * DD;
    unsigned short* wct     = wvt     + (size_t)DD * DD;
    unsigned short* wlxt    = wct     + (size_t)DD * DD;
    unsigned short* wla1t   = wlxt    + (size_t)DD * DD;
    p += ((size_t)DD * DD * 6 + (size_t)DD * 2 * DD) / 2;

    size_t used = (size_t)(p - (float*)d_ws);
    size_t totf = ws_size / sizeof(float);
    size_t availf = totf > used ? totf - used : 0;
    long long ecl = (long long)(availf / DD);   // 2 chunk buffers of DD bf16 = DD floats
    ecl = (ecl / 128) * 128;
    int EC = (int)(ecl > (long long)E ? (long long)E : ecl);
    if (EC < 2048) EC = 2048;
    unsigned short* c0 = (unsigned short*)p;        // ea16 / vs
    unsigned short* c1 = c0 + (size_t)EC * DD;      // kea / msg

    // ---- CSR build (once per launch) ----
    hipMemsetAsync(cursor, 0, N * sizeof(int), stream);
    deg_kernel<<<(E + 255) / 256, 256, 0, stream>>>(dstp, cursor);
    scan_kernel<<<1, 256, 0, stream>>>(cursor, rowptr, cursor);
    fill_perm<<<(E + 255) / 256, 256, 0, stream>>>(srcp, dstp, cursor, perm, src_s, dst_s);

    const float* xcur = x_in;
    float* outs[NL] = { xA, xB, (float*)d_out };

    for (int l = 0; l < NL; l++) {
        const float* Wck_l = Wck + (size_t)l * 2 * DD * DD;
        const float* bck_l = bck + (size_t)l * DD;
        const float* Wq_l  = Wq  + (size_t)l * DD * DD;
        const float* bq_l  = bq  + (size_t)l * DD;
        const float* Wv_l  = Wv  + (size_t)l * DD * DD;
        const float* bv_l  = bv  + (size_t)l * DD;
        const float* Waw_l = Waw + (size_t)l * HH * HH;
        const float* baw_l = baw + (size_t)l * HH;
        const float* Wc_l  = Wc  + (size_t)l * DD * DD;
        const float* bc_l  = bc  + (size_t)l * DD;
        const float* Wlx_l = Wlx + (size_t)l * DD * DD;
        const float* blx_l = blx + (size_t)l * DD;
        const float* Wla1_l = Wla1 + (size_t)l * 2 * DD * DD;
        const float* bla1_l = bla1 + (size_t)l * DD;
        const float* Wla2_l = Wla2 + (size_t)l * DD * 2;
        const float* bla2_l = bla2 + (size_t)l * 2;

        // ---- prep ----
        f2b_kernel<<<(N * 96 + 255) / 256, 256, 0, stream>>>(xcur, xb16, N * 96);
        transpose_w<<<dim3(DD / 32, DD / 32), 256, 0, stream>>>(Wq_l, wqt, DD);
        transpose_w<<<dim3(DD / 32, DD / 32), 256, 0, stream>>>(Wck_l, wcktopt, DD);
        transpose_w<<<dim3(DD / 32, DD / 32), 256, 0, stream>>>(Wck_l + (size_t)DD * DD, wckbott, DD);
        transpose_w<<<dim3(DD / 32, DD / 32), 256, 0, stream>>>(Wv_l, wvt, DD);
        transpose_w<<<dim3(DD / 32, DD / 32), 256, 0, stream>>>(Wc_l, wct, DD);
        transpose_w<<<dim3(DD / 32, DD / 32), 256, 0, stream>>>(Wlx_l, wlxt, DD);
        transpose_w<<<dim3(2 * DD / 32, DD / 32), 256, 0, stream>>>(Wla1_l, wla1t, 2 * DD);

        dim3 gn((N + 127) / 128, DD / 128);
        // ---- stage 1: node q/k-halves, then per-edge attention ----
        gemm_mfma<<<gn, 256, 0, stream>>>(xb16, nullptr, nullptr, nullptr, 0,
                                          wqt, bq_l, qn16, N, DD, 1);
        gemm_mfma<<<gn, 256, 0, stream>>>(xb16, nullptr, nullptr, nullptr, 0,
                                          wckbott, nullptr, kn16, N, DD, 1);
        for (int e0 = 0; e0 < E; e0 += EC) {
            int Mc = imin(EC, E - e0);
            dim3 gg((Mc + 127) / 128, DD / 128);
            f2b_gather<<<(Mc * 96 + 255) / 256, 256, 0, stream>>>(edge_attr, perm, e0, c0, Mc);
            gemm_mfma<<<gg, 256, 0, stream>>>(c0, nullptr, nullptr, nullptr, 0,
                                              wcktopt, bck_l, c1, Mc, DD, 1);
            aw_a_sorted<<<(Mc + 255) / 256, 256, 0, stream>>>(c1, kn16, qn16, Waw_l, baw_l,
                                                              src_s, dst_s, e0, Mc, abuf);
        }
        sc_gather<<<(N * HH + 255) / 256, 256, 0, stream>>>(abuf, rowptr, scbuf);
        att_kernel<<<(E * HH + 255) / 256, 256, 0, stream>>>(abuf, scbuf, dst_s);

        // ---- stage 2: messages -> h ----
        gemm_mfma<<<gn, 256, 0, stream>>>(xb16, nullptr, nullptr, nullptr, 0,
                                          wvt, bv_l, vn16, N, DD, 1);
        hipMemsetAsync(hbuf, 0, NB * sizeof(float), stream);
        for (int e0 = 0; e0 < E; e0 += EC) {
            int Mc = imin(EC, E - e0);
            dim3 gg((Mc + 127) / 128, DD / 128);
            vs_kernel<<<(Mc * 96 + 255) / 256, 256, 0, stream>>>(vn16, abuf, src_s, e0, c0, Mc);
            gemm_mfma<<<gg, 256, 0, stream>>>(c0, nullptr, nullptr, nullptr, 0,
                                              wct, bc_l, c1, Mc, DD, 1);
            h_gather<<<N, 256, 0, stream>>>(c1, rowptr, e0, e0 + Mc, hbuf);
        }

        // ---- stage 3: node update ----
        gemm_mfma<<<gn, 256, 0, stream>>>(xb16, nullptr, nullptr, nullptr, 0,
                                          wlxt, blx_l, lxb16, N, DD, 1);
        f2b_kernel<<<(N * 96 + 255) / 256, 256, 0, stream>>>(hbuf, hb16, N * 96);
        gemm_mfma<<<gn, 256, 0, stream>>>(lxb16, hb16, nullptr, nullptr, 0,
                                          wla1t, bla1_l, gb16, N, 2 * DD, 1);
        combine_kernel<<<(N + 3) / 4, 256, 0, stream>>>(gb16, Wla2_l, bla2_l,
                                                        xcur, hbuf, outs[l], N);
        xcur = outs[l];
    }
}

// Round 5
// 2731.785 us; speedup vs baseline: 10.0713x; 1.6791x over previous
//
#include <hip/hip_runtime.h>
#include <hip/hip_bf16.h>
#include <math.h>

#define DD 768
#define HH 8
#define DHH 96
#define NL 3
#define NN 20000
#define EE 100000

typedef __attribute__((ext_vector_type(8))) __bf16 bf16x8;
typedef __attribute__((ext_vector_type(4))) float f32x4;
typedef __attribute__((ext_vector_type(8))) unsigned short u16x8;

__host__ __device__ static inline int imin(int a, int b) { return a < b ? a : b; }

__device__ inline float b2f(unsigned short u) {
    union { unsigned int v; float f; } x; x.v = ((unsigned int)u) << 16; return x.f;
}
__device__ inline unsigned short f2b_rne(float f) {
    union { float f; unsigned int v; } x; x.f = f;
    unsigned int v = x.v;
    return (unsigned short)((v + 0x7FFFu + ((v >> 16) & 1u)) >> 16);
}

// ================= CSR build =================
__global__ void deg_kernel(const int* __restrict__ dst, int* __restrict__ cnt)
{
    int i = blockIdx.x * 256 + threadIdx.x;
    if (i < EE) atomicAdd(&cnt[dst[i]], 1);
}

__global__ __launch_bounds__(256)
void scan_kernel(const int* __restrict__ deg, int* __restrict__ rowptr, int* __restrict__ cursor)
{
    __shared__ int part[256];
    int t = threadIdx.x;
    const int per = (NN + 255) / 256;
    int lo = t * per, hi = imin(NN, lo + per);
    int s = 0;
    for (int i = lo; i < hi; i++) s += deg[i];
    part[t] = s;
    __syncthreads();
    if (t == 0) {
        int acc = 0;
        for (int i = 0; i < 256; i++) { int v = part[i]; part[i] = acc; acc += v; }
        rowptr[NN] = acc;
    }
    __syncthreads();
    int run = part[t];
    for (int i = lo; i < hi; i++) {
        rowptr[i] = run; cursor[i] = run;
        run += deg[i];
    }
}

__global__ void fill_perm(const int* __restrict__ src, const int* __restrict__ dst,
                          int* __restrict__ cursor, int* __restrict__ perm,
                          int* __restrict__ src_s, int* __restrict__ dst_s)
{
    int e = blockIdx.x * 256 + threadIdx.x;
    if (e >= EE) return;
    int d = dst[e];
    int pos = atomicAdd(&cursor[d], 1);
    perm[pos] = e;
    src_s[pos] = src[e];
    dst_s[pos] = d;
}

__global__ void degf_kernel(const int* __restrict__ rowptr, float* __restrict__ degf)
{
    int n = blockIdx.x * 256 + threadIdx.x;
    if (n < NN) degf[n] = (float)(rowptr[n + 1] - rowptr[n]);
}

// ================= conversions =================
__global__ void f2b_kernel(const float* __restrict__ in, unsigned short* __restrict__ out, int n8)
{
    int i = blockIdx.x * 256 + threadIdx.x;
    if (i >= n8) return;
    const float4* p = reinterpret_cast<const float4*>(in + (size_t)i * 8);
    float4 a = p[0], b = p[1];
    u16x8 o;
    o[0] = f2b_rne(a.x); o[1] = f2b_rne(a.y); o[2] = f2b_rne(a.z); o[3] = f2b_rne(a.w);
    o[4] = f2b_rne(b.x); o[5] = f2b_rne(b.y); o[6] = f2b_rne(b.z); o[7] = f2b_rne(b.w);
    *reinterpret_cast<u16x8*>(out + (size_t)i * 8) = o;
}

// gathered fp32 rows -> bf16 rows (edge_attr in perm order), full E
__global__ void f2b_gather(const float* __restrict__ in, const int* __restrict__ perm,
                           unsigned short* __restrict__ out)
{
    int i = blockIdx.x * 256 + threadIdx.x;
    if (i >= EE * 96) return;
    int m = i / 96;
    int d8 = (i % 96) * 8;
    int row = perm[m];
    const float4* p = reinterpret_cast<const float4*>(in + (size_t)row * DD + d8);
    float4 a = p[0], b = p[1];
    u16x8 o;
    o[0] = f2b_rne(a.x); o[1] = f2b_rne(a.y); o[2] = f2b_rne(a.z); o[3] = f2b_rne(a.w);
    o[4] = f2b_rne(b.x); o[5] = f2b_rne(b.y); o[6] = f2b_rne(b.z); o[7] = f2b_rne(b.w);
    *reinterpret_cast<u16x8*>(out + (size_t)m * DD + d8) = o;
}

// ---- W [Kin][768] fp32 (row stride 768) -> Wt[n*out_ld + out_off + k] bf16 ----
__global__ void transpose_w(const float* __restrict__ W, unsigned short* __restrict__ Wt,
                            int Kin, int out_ld, int out_off)
{
    __shared__ float tile[32][33];
    int kb = blockIdx.x * 32, nb = blockIdx.y * 32;
    int tx = threadIdx.x & 31, ty = threadIdx.x >> 5;
#pragma unroll
    for (int i = 0; i < 32; i += 8)
        tile[ty + i][tx] = W[(size_t)(kb + ty + i) * DD + nb + tx];
    __syncthreads();
#pragma unroll
    for (int i = 0; i < 32; i += 8)
        Wt[(size_t)(nb + ty + i) * out_ld + out_off + kb + tx] = f2b_rne(tile[tx][ty + i]);
}

// bf[n] = bla1[n] + sum_k blx[k] * Wla1_top[k][n]
__global__ void biasf_kernel(const float* __restrict__ blx, const float* __restrict__ Wla1,
                             const float* __restrict__ bla1, float* __restrict__ bf)
{
    int n = blockIdx.x * 256 + threadIdx.x;
    if (n >= DD) return;
    float s = bla1[n];
    for (int k = 0; k < DD; k++) s += blx[k] * Wla1[(size_t)k * DD + n];
    bf[n] = s;
}

__global__ void biasqkv_kernel(const float* __restrict__ bq, const float* __restrict__ bv,
                               float* __restrict__ bqkv)
{
    int i = blockIdx.x * 256 + threadIdx.x;
    if (i >= 3 * DD) return;
    float v = 0.f;
    if (i < DD) v = bq[i];
    else if (i >= 2 * DD) v = bv[i - 2 * DD];
    bqkv[i] = v;
}

// ================= MFMA GEMM =================
// C[M,Nw] = concat(A0,A1)[M,K] @ W + bias*rowscale ; Wt [Nw][K] bf16 n-major.
// LDS [128 r][64 k] bf16, XOR-swizzle via pre-swizzled global source + same XOR on read.
// grid: (Nw/128, ceil(M/128)) — bn fastest so concurrent blocks share A via L3.
__global__ __launch_bounds__(256)
void gemm_mfma(const unsigned short* __restrict__ A0,
               const unsigned short* __restrict__ A1,
               const unsigned short* __restrict__ Wt,
               const float* __restrict__ bias,
               const float* __restrict__ rowscale,
               float* __restrict__ C32,
               unsigned short* __restrict__ C16,
               int M, int K, int Nw)
{
    __shared__ __align__(16) char smem[32768];
    char* As = smem;
    char* Bs = smem + 16384;
    const int t = threadIdx.x;
    const int l = t & 63;
    const int w = t >> 6;
    const int wm = w >> 1, wn = w & 1;
    const int bn = blockIdx.x, bm = blockIdx.y;

    const int srow = t >> 3;                      // 0..31
    const int ssrc = ((t & 7) ^ (srow & 7)) * 8;  // swizzled source col (bf16)

    const int lane_r = l & 15;
    const int lane_k = l >> 4;

    f32x4 acc[4][4];
#pragma unroll
    for (int m = 0; m < 4; m++)
#pragma unroll
        for (int n = 0; n < 4; n++) acc[m][n] = (f32x4){0.f, 0.f, 0.f, 0.f};

    for (int k0 = 0; k0 < K; k0 += 64) {
        const unsigned short* Ap; int kbase;
        if (k0 < DD) { Ap = A0; kbase = k0; }
        else         { Ap = A1; kbase = k0 - DD; }
#pragma unroll
        for (int i = 0; i < 4; i++) {
            int rt = i * 32 + srow;
            int grow = bm * 128 + rt;
            char* ldstA = As + ((i * 32 + w * 8) << 7);
            if (grow < M) {
                const unsigned short* g = Ap + (size_t)grow * DD + kbase + ssrc;
                __builtin_amdgcn_global_load_lds(
                    (const __attribute__((address_space(1))) void*)g,
                    (__attribute__((address_space(3))) void*)ldstA, 16, 0, 0);
            }
            int gn = bn * 128 + rt;
            const unsigned short* gB = Wt + (size_t)gn * K + k0 + ssrc;
            char* ldstB = Bs + ((i * 32 + w * 8) << 7);
            __builtin_amdgcn_global_load_lds(
                (const __attribute__((address_space(1))) void*)gB,
                (__attribute__((address_space(3))) void*)ldstB, 16, 0, 0);
        }
        __syncthreads();
#pragma unroll
        for (int kk = 0; kk < 2; kk++) {
            bf16x8 af[4], bfr[4];
#pragma unroll
            for (int m = 0; m < 4; m++) {
                int r = wm * 64 + m * 16 + lane_r;
                int slot = (kk * 4 + lane_k) ^ (r & 7);
                af[m] = *reinterpret_cast<const bf16x8*>(As + r * 128 + slot * 16);
            }
#pragma unroll
            for (int n = 0; n < 4; n++) {
                int r = wn * 64 + n * 16 + lane_r;
                int slot = (kk * 4 + lane_k) ^ (r & 7);
                bfr[n] = *reinterpret_cast<const bf16x8*>(Bs + r * 128 + slot * 16);
            }
#pragma unroll
            for (int m = 0; m < 4; m++)
#pragma unroll
                for (int n = 0; n < 4; n++)
                    acc[m][n] = __builtin_amdgcn_mfma_f32_16x16x32_bf16(
                        af[m], bfr[n], acc[m][n], 0, 0, 0);
        }
        __syncthreads();
    }
#pragma unroll
    for (int n = 0; n < 4; n++) {
        int col = bn * 128 + wn * 64 + n * 16 + lane_r;
        float badd = bias ? bias[col] : 0.f;
#pragma unroll
        for (int m = 0; m < 4; m++) {
            int r0 = bm * 128 + wm * 64 + m * 16 + lane_k * 4;
#pragma unroll
            for (int j = 0; j < 4; j++) {
                int r = r0 + j;
                if (r < M) {
                    float bs = rowscale ? rowscale[r] : 1.f;
                    float val = acc[m][n][j] + badd * bs;
                    if (C32) C32[(size_t)r * Nw + col] = val;
                    if (C16) C16[(size_t)r * Nw + col] = f2b_rne(val);
                }
            }
        }
    }
}

// ================= edge attention =================
// per sorted-edge j: k = kea[j] + kn[src]; aw[h]=(q.k)/sqrt(D); a=exp(lrelu(aw)@Waw+baw)
__global__ __launch_bounds__(256)
void aw_a_sorted(const unsigned short* __restrict__ kea,
                 const unsigned short* __restrict__ qkv,
                 const float* __restrict__ Waw, const float* __restrict__ baw,
                 const int* __restrict__ src_s, const int* __restrict__ dst_s,
                 float* __restrict__ abuf)
{
    int j = blockIdx.x * 256 + threadIdx.x;
    if (j >= EE) return;
    const u16x8* ke = reinterpret_cast<const u16x8*>(kea + (size_t)j * DD);
    const u16x8* kr = reinterpret_cast<const u16x8*>(qkv + (size_t)src_s[j] * (3 * DD) + DD);
    const u16x8* qr = reinterpret_cast<const u16x8*>(qkv + (size_t)dst_s[j] * (3 * DD));
    constexpr float rs = 0.03608439182435161f; // 1/sqrt(768)
    float t[HH];
#pragma unroll
    for (int h = 0; h < HH; h++) {
        float s = 0.f;
#pragma unroll
        for (int c = 0; c < 12; c++) {
            u16x8 qv = qr[h * 12 + c];
            u16x8 k1 = ke[h * 12 + c];
            u16x8 k2 = kr[h * 12 + c];
#pragma unroll
            for (int x = 0; x < 8; x++)
                s = fmaf(b2f(qv[x]), b2f(k1[x]) + b2f(k2[x]), s);
        }
        float aw = s * rs;
        t[h] = aw > 0.f ? aw : 0.2f * aw;
    }
#pragma unroll
    for (int h = 0; h < HH; h++) {
        float z = baw[h];
#pragma unroll
        for (int h2 = 0; h2 < HH; h2++) z = fmaf(t[h2], Waw[h2 * HH + h], z);
        abuf[(size_t)j * HH + h] = expf(z);
    }
}

// agg[n] = (sum_j a_j (*) v[src_j]) / sc[n]  — one block per node
__global__ __launch_bounds__(256)
void agg_kernel(const unsigned short* __restrict__ qkv, const float* __restrict__ abuf,
                const int* __restrict__ rowptr, const int* __restrict__ src_s,
                unsigned short* __restrict__ agg)
{
    __shared__ float inv8[HH];
    int n = blockIdx.x;
    int jlo = rowptr[n], jhi = rowptr[n + 1];
    int t = threadIdx.x;
    if (t < HH) {
        float s = 0.f;
        for (int j = jlo; j < jhi; j++) s += abuf[(size_t)j * HH + t];
        inv8[t] = (s == 0.f) ? 1.f : 1.f / s;
    }
    __syncthreads();
    int c0 = t, c1 = t + 256, c2 = t + 512;
    int h0 = c0 / DHH, h1 = c1 / DHH, h2 = c2 / DHH;
    float a0 = 0.f, a1 = 0.f, a2 = 0.f;
    for (int j = jlo; j < jhi; j++) {
        const unsigned short* v = qkv + (size_t)src_s[j] * (3 * DD) + 2 * DD;
        const float* ab = abuf + (size_t)j * HH;
        a0 = fmaf(ab[h0], b2f(v[c0]), a0);
        a1 = fmaf(ab[h1], b2f(v[c1]), a1);
        a2 = fmaf(ab[h2], b2f(v[c2]), a2);
    }
    unsigned short* o = agg + (size_t)n * DD;
    o[c0] = f2b_rne(a0 * inv8[h0]);
    o[c1] = f2b_rne(a1 * inv8[h1]);
    o[c2] = f2b_rne(a2 * inv8[h2]);
}

// one wave per node: z = lrelu(g)@Wla2 + bla2 ; la = softmax(z) ; out = x*la0 + h*la1
// reads x as bf16; writes bf16 x for next layer and optionally fp32 out
__global__ __launch_bounds__(256)
void combine_kernel(const unsigned short* __restrict__ g, const float* __restrict__ Wla2,
                    const float* __restrict__ bla2, unsigned short* __restrict__ x16,
                    const float* __restrict__ h, float* __restrict__ outf, int Nn)
{
    int w = threadIdx.x >> 6;
    int lane = threadIdx.x & 63;
    int n = blockIdx.x * 4 + w;
    if (n >= Nn) return;
    float z0 = 0.f, z1 = 0.f;
#pragma unroll
    for (int p = 0; p < 3; p++) {
        int d = p * 256 + lane * 4;
        const unsigned short* gp = g + (size_t)n * DD + d;
#pragma unroll
        for (int j = 0; j < 4; j++) {
            float gv = b2f(gp[j]);
            float tt = gv > 0.f ? gv : 0.2f * gv;
            z0 = fmaf(tt, Wla2[(d + j) * 2 + 0], z0);
            z1 = fmaf(tt, Wla2[(d + j) * 2 + 1], z1);
        }
    }
#pragma unroll
    for (int off = 32; off > 0; off >>= 1) {
        z0 += __shfl_xor(z0, off);
        z1 += __shfl_xor(z1, off);
    }
    z0 += bla2[0]; z1 += bla2[1];
    float mx = fmaxf(z0, z1);
    float e0v = expf(z0 - mx), e1v = expf(z1 - mx);
    float inv = 1.f / (e0v + e1v);
    float la0 = e0v * inv, la1 = e1v * inv;
#pragma unroll
    for (int p = 0; p < 3; p++) {
        int d = p * 256 + lane * 4;
        unsigned short* xp = x16 + (size_t)n * DD + d;
        const float* hp = h + (size_t)n * DD + d;
        float o[4];
#pragma unroll
        for (int j = 0; j < 4; j++)
            o[j] = b2f(xp[j]) * la0 + hp[j] * la1;
#pragma unroll
        for (int j = 0; j < 4; j++) xp[j] = f2b_rne(o[j]);
        if (outf) {
            float4 ov = make_float4(o[0], o[1], o[2], o[3]);
            *reinterpret_cast<float4*>((float*)outf + (size_t)n * DD + d) = ov;
        }
    }
}

extern "C" void kernel_launch(void* const* d_in, const int* in_sizes, int n_in,
                              void* d_out, int out_size, void* d_ws, size_t ws_size,
                              hipStream_t stream)
{
    const int N = NN, E = EE;
    const float* x_in      = (const float*)d_in[0];
    const float* edge_attr = (const float*)d_in[1];
    const float* Wck = (const float*)d_in[2];
    const float* bck = (const float*)d_in[3];
    const float* Wq  = (const float*)d_in[4];
    const float* bq  = (const float*)d_in[5];
    const float* Wv  = (const float*)d_in[6];
    const float* bv  = (const float*)d_in[7];
    const float* Waw = (const float*)d_in[8];
    const float* baw = (const float*)d_in[9];
    const float* Wc  = (const float*)d_in[10];
    const float* bc  = (const float*)d_in[11];
    const float* Wlx = (const float*)d_in[12];
    const float* blx = (const float*)d_in[13];
    const float* Wla1 = (const float*)d_in[14];
    const float* bla1 = (const float*)d_in[15];
    const float* Wla2 = (const float*)d_in[16];
    const float* bla2 = (const float*)d_in[17];
    const int* eidx = (const int*)d_in[18];
    const int* srcp = eidx;       // edge_index[0]
    const int* dstp = eidx + E;   // edge_index[1]

    float* p = (float*)d_ws;
    const size_t NB = (size_t)N * DD;   // 15.36M
    float* hbuf  = p; p += NB;
    float* abuf  = p; p += (size_t)E * HH;
    float* degf  = p; p += N;
    float* wfx32 = p; p += (size_t)DD * DD;
    float* bfbuf = p; p += DD;
    float* bqkvb = p; p += 3 * DD;
    // int region
    int* rowptr = (int*)p;
    int* cursor = rowptr + (N + 1);
    int* perm   = cursor + N;
    int* src_s  = perm + E;
    int* dst_s  = src_s + E;
    p += (size_t)(2 * N + 1 + 3 * E + 63) / 64 * 64;
    // bf16 regions (counted in floats = elems/2)
    unsigned short* xb16  = (unsigned short*)p; p += NB / 2;
    unsigned short* hb16  = (unsigned short*)p; p += NB / 2;
    unsigned short* qkv16 = (unsigned short*)p; p += 3 * NB / 2;   // [N][2304]
    unsigned short* ea16  = (unsigned short*)p; p += (size_t)E * DD / 2;
    unsigned short* kea16 = (unsigned short*)p; p += (size_t)E * DD / 2;
    unsigned short* agg16 = kea16;                 // reuse after aw_a done
    unsigned short* gb16  = qkv16;                 // reuse after agg done
    // weights
    unsigned short* wqkvt  = (unsigned short*)p; p += (size_t)3 * DD * DD / 2; // [2304][768]
    unsigned short* wcktopt= (unsigned short*)p; p += (size_t)DD * DD / 2;
    unsigned short* wct    = (unsigned short*)p; p += (size_t)DD * DD / 2;
    unsigned short* wla1tt = (unsigned short*)p; p += (size_t)DD * DD / 2;
    unsigned short* wst3   = (unsigned short*)p; p += (size_t)DD * 2 * DD / 2; // [768][1536]
    unsigned short* wlx16  = (unsigned short*)p; p += (size_t)DD * DD / 2;

    // ---- setup (once) ----
    hipMemsetAsync(cursor, 0, N * sizeof(int), stream);
    deg_kernel<<<(E + 255) / 256, 256, 0, stream>>>(dstp, cursor);
    scan_kernel<<<1, 256, 0, stream>>>(cursor, rowptr, cursor);
    fill_perm<<<(E + 255) / 256, 256, 0, stream>>>(srcp, dstp, cursor, perm, src_s, dst_s);
    degf_kernel<<<(N + 255) / 256, 256, 0, stream>>>(rowptr, degf);
    f2b_gather<<<(E * 96 + 255) / 256, 256, 0, stream>>>(edge_attr, perm, ea16);
    f2b_kernel<<<(N * 96 + 255) / 256, 256, 0, stream>>>(x_in, xb16, N * 96);

    for (int l = 0; l < NL; l++) {
        const float* Wck_l = Wck + (size_t)l * 2 * DD * DD;
        const float* bck_l = bck + (size_t)l * DD;
        const float* Wq_l  = Wq  + (size_t)l * DD * DD;
        const float* bq_l  = bq  + (size_t)l * DD;
        const float* Wv_l  = Wv  + (size_t)l * DD * DD;
        const float* bv_l  = bv  + (size_t)l * DD;
        const float* Waw_l = Waw + (size_t)l * HH * HH;
        const float* baw_l = baw + (size_t)l * HH;
        const float* Wc_l  = Wc  + (size_t)l * DD * DD;
        const float* bc_l  = bc  + (size_t)l * DD;
        const float* Wlx_l = Wlx + (size_t)l * DD * DD;
        const float* blx_l = blx + (size_t)l * DD;
        const float* Wla1_l = Wla1 + (size_t)l * 2 * DD * DD;
        const float* bla1_l = bla1 + (size_t)l * DD;
        const float* Wla2_l = Wla2 + (size_t)l * DD * 2;
        const float* bla2_l = bla2 + (size_t)l * 2;

        // ---- weight prep ----
        dim3 gt(DD / 32, DD / 32);
        transpose_w<<<gt, 256, 0, stream>>>(Wq_l, wqkvt, DD, DD, 0);
        transpose_w<<<gt, 256, 0, stream>>>(Wck_l + (size_t)DD * DD, wqkvt + (size_t)DD * DD, DD, DD, 0);
        transpose_w<<<gt, 256, 0, stream>>>(Wv_l, wqkvt + (size_t)2 * DD * DD, DD, DD, 0);
        transpose_w<<<gt, 256, 0, stream>>>(Wck_l, wcktopt, DD, DD, 0);
        transpose_w<<<gt, 256, 0, stream>>>(Wc_l, wct, DD, DD, 0);
        transpose_w<<<gt, 256, 0, stream>>>(Wla1_l, wla1tt, DD, DD, 0);
        transpose_w<<<gt, 256, 0, stream>>>(Wla1_l + (size_t)DD * DD, wst3, DD, 2 * DD, DD);
        f2b_kernel<<<(DD * 96 + 255) / 256, 256, 0, stream>>>(Wlx_l, wlx16, DD * 96);
        gemm_mfma<<<dim3(6, 6), 256, 0, stream>>>(wlx16, nullptr, wla1tt, nullptr, nullptr,
                                                  wfx32, nullptr, DD, DD, DD);
        transpose_w<<<gt, 256, 0, stream>>>(wfx32, wst3, DD, 2 * DD, 0);
        biasf_kernel<<<3, 256, 0, stream>>>(blx_l, Wla1_l, bla1_l, bfbuf);
        biasqkv_kernel<<<9, 256, 0, stream>>>(bq_l, bv_l, bqkvb);

        // ---- qkv node GEMM [N][2304] ----
        gemm_mfma<<<dim3(18, (N + 127) / 128), 256, 0, stream>>>(
            xb16, nullptr, wqkvt, bqkvb, nullptr, nullptr, qkv16, N, DD, 3 * DD);
        // ---- kea edge GEMM [E][768] ----
        gemm_mfma<<<dim3(6, (E + 127) / 128), 256, 0, stream>>>(
            ea16, nullptr, wcktopt, bck_l, nullptr, nullptr, kea16, E, DD, DD);
        // ---- attention coefficients ----
        aw_a_sorted<<<(E + 255) / 256, 256, 0, stream>>>(kea16, qkv16, Waw_l, baw_l,
                                                         src_s, dst_s, abuf);
        // ---- segmented weighted sum (normalization folded in) ----
        agg_kernel<<<N, 256, 0, stream>>>(qkv16, abuf, rowptr, src_s, agg16);
        // ---- h = agg @ Wc + deg*bc (dual fp32+bf16 out) ----
        gemm_mfma<<<dim3(6, (N + 127) / 128), 256, 0, stream>>>(
            agg16, nullptr, wct, bc_l, degf, hbuf, hb16, N, DD, DD);
        // ---- g = x@Wfx + h@Wla1_bot + bf ----
        gemm_mfma<<<dim3(6, (N + 127) / 128), 256, 0, stream>>>(
            xb16, hb16, wst3, bfbuf, nullptr, nullptr, gb16, N, 2 * DD, DD);
        // ---- gated combine ----
        combine_kernel<<<(N + 3) / 4, 256, 0, stream>>>(
            gb16, Wla2_l, bla2_l, xb16, hbuf,
            (l == NL - 1) ? (float*)d_out : nullptr, N);
    }
}

// Round 6
// 2406.437 us; speedup vs baseline: 11.4329x; 1.1352x over previous
//
#include <hip/hip_runtime.h>
#include <hip/hip_bf16.h>
#include <math.h>

#define DD 768
#define HH 8
#define DHH 96
#define NL 3
#define NN 20000
#define EE 100000

typedef __attribute__((ext_vector_type(8))) __bf16 bf16x8;
typedef __attribute__((ext_vector_type(4))) float f32x4;
typedef __attribute__((ext_vector_type(8))) unsigned short u16x8;

__host__ __device__ static inline int imin(int a, int b) { return a < b ? a : b; }

__device__ inline float b2f(unsigned short u) {
    union { unsigned int v; float f; } x; x.v = ((unsigned int)u) << 16; return x.f;
}
__device__ inline unsigned short f2b_rne(float f) {
    union { float f; unsigned int v; } x; x.f = f;
    unsigned int v = x.v;
    return (unsigned short)((v + 0x7FFFu + ((v >> 16) & 1u)) >> 16);
}

// ================= CSR build =================
__global__ void deg_kernel(const int* __restrict__ dst, int* __restrict__ cnt)
{
    int i = blockIdx.x * 256 + threadIdx.x;
    if (i < EE) atomicAdd(&cnt[dst[i]], 1);
}

__global__ __launch_bounds__(256)
void scan_kernel(const int* __restrict__ deg, int* __restrict__ rowptr, int* __restrict__ cursor)
{
    __shared__ int part[256];
    int t = threadIdx.x;
    const int per = (NN + 255) / 256;
    int lo = t * per, hi = imin(NN, lo + per);
    int s = 0;
    for (int i = lo; i < hi; i++) s += deg[i];
    part[t] = s;
    __syncthreads();
    if (t == 0) {
        int acc = 0;
        for (int i = 0; i < 256; i++) { int v = part[i]; part[i] = acc; acc += v; }
        rowptr[NN] = acc;
    }
    __syncthreads();
    int run = part[t];
    for (int i = lo; i < hi; i++) {
        rowptr[i] = run; cursor[i] = run;
        run += deg[i];
    }
}

__global__ void fill_perm(const int* __restrict__ src, const int* __restrict__ dst,
                          int* __restrict__ cursor, int* __restrict__ perm,
                          int* __restrict__ src_s, int* __restrict__ dst_s)
{
    int e = blockIdx.x * 256 + threadIdx.x;
    if (e >= EE) return;
    int d = dst[e];
    int pos = atomicAdd(&cursor[d], 1);
    perm[pos] = e;
    src_s[pos] = src[e];
    dst_s[pos] = d;
}

__global__ void degf_kernel(const int* __restrict__ rowptr, float* __restrict__ degf)
{
    int n = blockIdx.x * 256 + threadIdx.x;
    if (n < NN) degf[n] = (float)(rowptr[n + 1] - rowptr[n]);
}

// ================= conversions =================
__global__ void f2b_kernel(const float* __restrict__ in, unsigned short* __restrict__ out, int n8)
{
    int i = blockIdx.x * 256 + threadIdx.x;
    if (i >= n8) return;
    const float4* p = reinterpret_cast<const float4*>(in + (size_t)i * 8);
    float4 a = p[0], b = p[1];
    u16x8 o;
    o[0] = f2b_rne(a.x); o[1] = f2b_rne(a.y); o[2] = f2b_rne(a.z); o[3] = f2b_rne(a.w);
    o[4] = f2b_rne(b.x); o[5] = f2b_rne(b.y); o[6] = f2b_rne(b.z); o[7] = f2b_rne(b.w);
    *reinterpret_cast<u16x8*>(out + (size_t)i * 8) = o;
}

__global__ void f2b_gather(const float* __restrict__ in, const int* __restrict__ perm,
                           unsigned short* __restrict__ out)
{
    int i = blockIdx.x * 256 + threadIdx.x;
    if (i >= EE * 96) return;
    int m = i / 96;
    int d8 = (i % 96) * 8;
    int row = perm[m];
    const float4* p = reinterpret_cast<const float4*>(in + (size_t)row * DD + d8);
    float4 a = p[0], b = p[1];
    u16x8 o;
    o[0] = f2b_rne(a.x); o[1] = f2b_rne(a.y); o[2] = f2b_rne(a.z); o[3] = f2b_rne(a.w);
    o[4] = f2b_rne(b.x); o[5] = f2b_rne(b.y); o[6] = f2b_rne(b.z); o[7] = f2b_rne(b.w);
    *reinterpret_cast<u16x8*>(out + (size_t)m * DD + d8) = o;
}

// ---- W [Kin][768] fp32 (row stride 768) -> Wt[n*out_ld + out_off + k] bf16 ----
__global__ void transpose_w(const float* __restrict__ W, unsigned short* __restrict__ Wt,
                            int Kin, int out_ld, int out_off)
{
    __shared__ float tile[32][33];
    int kb = blockIdx.x * 32, nb = blockIdx.y * 32;
    int tx = threadIdx.x & 31, ty = threadIdx.x >> 5;
#pragma unroll
    for (int i = 0; i < 32; i += 8)
        tile[ty + i][tx] = W[(size_t)(kb + ty + i) * DD + nb + tx];
    __syncthreads();
#pragma unroll
    for (int i = 0; i < 32; i += 8)
        Wt[(size_t)(nb + ty + i) * out_ld + out_off + kb + tx] = f2b_rne(tile[tx][ty + i]);
}

__global__ void biasf_kernel(const float* __restrict__ blx, const float* __restrict__ Wla1,
                             const float* __restrict__ bla1, float* __restrict__ bf)
{
    int n = blockIdx.x * 256 + threadIdx.x;
    if (n >= DD) return;
    float s = bla1[n];
    for (int k = 0; k < DD; k++) s += blx[k] * Wla1[(size_t)k * DD + n];
    bf[n] = s;
}

__global__ void biasqkv_kernel(const float* __restrict__ bq, const float* __restrict__ bv,
                               float* __restrict__ bqkv)
{
    int i = blockIdx.x * 256 + threadIdx.x;
    if (i >= 3 * DD) return;
    float v = 0.f;
    if (i < DD) v = bq[i];
    else if (i >= 2 * DD) v = bv[i - 2 * DD];
    bqkv[i] = v;
}

// ================= MFMA GEMM =================
// C[M,Nw] = concat(A0,A1)[M,K] @ W + bias*rowscale ; Wt [Nw][K] bf16 n-major.
// XCD-chunked bijective block swizzle (same-A-tile col blocks land on one XCD's L2).
// bf16 C written via LDS staging for full-line coalesced stores.
__global__ __launch_bounds__(256)
void gemm_mfma(const unsigned short* __restrict__ A0,
               const unsigned short* __restrict__ A1,
               const unsigned short* __restrict__ Wt,
               const float* __restrict__ bias,
               const float* __restrict__ rowscale,
               float* __restrict__ C32,
               unsigned short* __restrict__ C16,
               int M, int K, int Nw)
{
    __shared__ __align__(16) char smem[32768];
    char* As = smem;
    char* Bs = smem + 16384;
    const int t = threadIdx.x;
    const int l = t & 63;
    const int w = t >> 6;
    const int wm = w >> 1, wn = w & 1;

    // ---- XCD-chunked bijective swizzle (m204) ----
    const int gx = gridDim.x;
    const int nwg = gx * gridDim.y;
    const int lin = blockIdx.y * gx + blockIdx.x;
    const int xcd = lin & 7, pos = lin >> 3;
    const int q8 = nwg >> 3, r8 = nwg & 7;
    const int base = (xcd < r8) ? xcd * (q8 + 1) : r8 * (q8 + 1) + (xcd - r8) * q8;
    const int swz = base + pos;
    const int bn = swz % gx, bm = swz / gx;

    const int srow = t >> 3;                      // 0..31
    const int ssrc = ((t & 7) ^ (srow & 7)) * 8;  // swizzled source col (bf16)

    const int lane_r = l & 15;
    const int lane_k = l >> 4;

    f32x4 acc[4][4];
#pragma unroll
    for (int m = 0; m < 4; m++)
#pragma unroll
        for (int n = 0; n < 4; n++) acc[m][n] = (f32x4){0.f, 0.f, 0.f, 0.f};

    for (int k0 = 0; k0 < K; k0 += 64) {
        const unsigned short* Ap; int kbase;
        if (k0 < DD) { Ap = A0; kbase = k0; }
        else         { Ap = A1; kbase = k0 - DD; }
#pragma unroll
        for (int i = 0; i < 4; i++) {
            int rt = i * 32 + srow;
            int grow = bm * 128 + rt;
            char* ldstA = As + ((i * 32 + w * 8) << 7);
            if (grow < M) {
                const unsigned short* g = Ap + (size_t)grow * DD + kbase + ssrc;
                __builtin_amdgcn_global_load_lds(
                    (const __attribute__((address_space(1))) void*)g,
                    (__attribute__((address_space(3))) void*)ldstA, 16, 0, 0);
            }
            int gn = bn * 128 + rt;
            const unsigned short* gB = Wt + (size_t)gn * K + k0 + ssrc;
            char* ldstB = Bs + ((i * 32 + w * 8) << 7);
            __builtin_amdgcn_global_load_lds(
                (const __attribute__((address_space(1))) void*)gB,
                (__attribute__((address_space(3))) void*)ldstB, 16, 0, 0);
        }
        __syncthreads();
#pragma unroll
        for (int kk = 0; kk < 2; kk++) {
            bf16x8 af[4], bfr[4];
#pragma unroll
            for (int m = 0; m < 4; m++) {
                int r = wm * 64 + m * 16 + lane_r;
                int slot = (kk * 4 + lane_k) ^ (r & 7);
                af[m] = *reinterpret_cast<const bf16x8*>(As + r * 128 + slot * 16);
            }
#pragma unroll
            for (int n = 0; n < 4; n++) {
                int r = wn * 64 + n * 16 + lane_r;
                int slot = (kk * 4 + lane_k) ^ (r & 7);
                bfr[n] = *reinterpret_cast<const bf16x8*>(Bs + r * 128 + slot * 16);
            }
#pragma unroll
            for (int m = 0; m < 4; m++)
#pragma unroll
                for (int n = 0; n < 4; n++)
                    acc[m][n] = __builtin_amdgcn_mfma_f32_16x16x32_bf16(
                        af[m], bfr[n], acc[m][n], 0, 0, 0);
        }
        __syncthreads();
    }

    // ---- epilogue ----
    unsigned short* cs = (unsigned short*)smem;   // 128x128 bf16 staging (32 KB)
#pragma unroll
    for (int n = 0; n < 4; n++) {
        int lcol = wn * 64 + n * 16 + lane_r;
        float badd = bias ? bias[bn * 128 + lcol] : 0.f;
#pragma unroll
        for (int m = 0; m < 4; m++) {
            int lr0 = wm * 64 + m * 16 + lane_k * 4;
#pragma unroll
            for (int j = 0; j < 4; j++) {
                int lr = lr0 + j;
                int r = bm * 128 + lr;
                float bs = rowscale ? (r < M ? rowscale[r] : 0.f) : 1.f;
                float val = acc[m][n][j] + badd * bs;
                if (C32 && r < M) C32[(size_t)r * Nw + bn * 128 + lcol] = val;
                if (C16) cs[lr * 128 + lcol] = f2b_rne(val);
            }
        }
    }
    if (C16) {
        __syncthreads();
        int rr = t >> 1, half = t & 1;
        int grow = bm * 128 + rr;
        if (grow < M) {
            u16x8* dst = reinterpret_cast<u16x8*>(C16 + (size_t)grow * Nw + bn * 128 + half * 64);
            const u16x8* s = reinterpret_cast<const u16x8*>(cs + rr * 128 + half * 64);
#pragma unroll
            for (int c = 0; c < 8; c++) dst[c] = s[c];
        }
    }
}

// ================= edge attention =================
__global__ __launch_bounds__(256)
void aw_a_sorted(const unsigned short* __restrict__ kea,
                 const unsigned short* __restrict__ qkv,
                 const float* __restrict__ Waw, const float* __restrict__ baw,
                 const int* __restrict__ src_s, const int* __restrict__ dst_s,
                 float* __restrict__ abuf)
{
    int j = blockIdx.x * 256 + threadIdx.x;
    if (j >= EE) return;
    const u16x8* ke = reinterpret_cast<const u16x8*>(kea + (size_t)j * DD);
    const u16x8* kr = reinterpret_cast<const u16x8*>(qkv + (size_t)src_s[j] * (3 * DD) + DD);
    const u16x8* qr = reinterpret_cast<const u16x8*>(qkv + (size_t)dst_s[j] * (3 * DD));
    constexpr float rs = 0.03608439182435161f; // 1/sqrt(768)
    float t[HH];
#pragma unroll
    for (int h = 0; h < HH; h++) {
        float s = 0.f;
#pragma unroll
        for (int c = 0; c < 12; c++) {
            u16x8 qv = qr[h * 12 + c];
            u16x8 k1 = ke[h * 12 + c];
            u16x8 k2 = kr[h * 12 + c];
#pragma unroll
            for (int x = 0; x < 8; x++)
                s = fmaf(b2f(qv[x]), b2f(k1[x]) + b2f(k2[x]), s);
        }
        float aw = s * rs;
        t[h] = aw > 0.f ? aw : 0.2f * aw;
    }
#pragma unroll
    for (int h = 0; h < HH; h++) {
        float z = baw[h];
#pragma unroll
        for (int h2 = 0; h2 < HH; h2++) z = fmaf(t[h2], Waw[h2 * HH + h], z);
        abuf[(size_t)j * HH + h] = expf(z);
    }
}

// agg[n] = (sum_j a_j (*) v[src_j]) / sc[n]  — one block per node
__global__ __launch_bounds__(256)
void agg_kernel(const unsigned short* __restrict__ qkv, const float* __restrict__ abuf,
                const int* __restrict__ rowptr, const int* __restrict__ src_s,
                unsigned short* __restrict__ agg)
{
    __shared__ float inv8[HH];
    int n = blockIdx.x;
    int jlo = rowptr[n], jhi = rowptr[n + 1];
    int t = threadIdx.x;
    if (t < HH) {
        float s = 0.f;
        for (int j = jlo; j < jhi; j++) s += abuf[(size_t)j * HH + t];
        inv8[t] = (s == 0.f) ? 1.f : 1.f / s;
    }
    __syncthreads();
    int c0 = t, c1 = t + 256, c2 = t + 512;
    int h0 = c0 / DHH, h1 = c1 / DHH, h2 = c2 / DHH;
    float a0 = 0.f, a1 = 0.f, a2 = 0.f;
    for (int j = jlo; j < jhi; j++) {
        const unsigned short* v = qkv + (size_t)src_s[j] * (3 * DD) + 2 * DD;
        const float* ab = abuf + (size_t)j * HH;
        a0 = fmaf(ab[h0], b2f(v[c0]), a0);
        a1 = fmaf(ab[h1], b2f(v[c1]), a1);
        a2 = fmaf(ab[h2], b2f(v[c2]), a2);
    }
    unsigned short* o = agg + (size_t)n * DD;
    o[c0] = f2b_rne(a0 * inv8[h0]);
    o[c1] = f2b_rne(a1 * inv8[h1]);
    o[c2] = f2b_rne(a2 * inv8[h2]);
}

// one wave per node: z = lrelu(g)@Wla2 + bla2 ; la = softmax(z) ; out = x*la0 + h*la1
__global__ __launch_bounds__(256)
void combine_kernel(const unsigned short* __restrict__ g, const float* __restrict__ Wla2,
                    const float* __restrict__ bla2, unsigned short* __restrict__ x16,
                    const float* __restrict__ h, float* __restrict__ outf, int Nn)
{
    int w = threadIdx.x >> 6;
    int lane = threadIdx.x & 63;
    int n = blockIdx.x * 4 + w;
    if (n >= Nn) return;
    float z0 = 0.f, z1 = 0.f;
#pragma unroll
    for (int p = 0; p < 3; p++) {
        int d = p * 256 + lane * 4;
        const unsigned short* gp = g + (size_t)n * DD + d;
#pragma unroll
        for (int j = 0; j < 4; j++) {
            float gv = b2f(gp[j]);
            float tt = gv > 0.f ? gv : 0.2f * gv;
            z0 = fmaf(tt, Wla2[(d + j) * 2 + 0], z0);
            z1 = fmaf(tt, Wla2[(d + j) * 2 + 1], z1);
        }
    }
#pragma unroll
    for (int off = 32; off > 0; off >>= 1) {
        z0 += __shfl_xor(z0, off);
        z1 += __shfl_xor(z1, off);
    }
    z0 += bla2[0]; z1 += bla2[1];
    float mx = fmaxf(z0, z1);
    float e0v = expf(z0 - mx), e1v = expf(z1 - mx);
    float inv = 1.f / (e0v + e1v);
    float la0 = e0v * inv, la1 = e1v * inv;
#pragma unroll
    for (int p = 0; p < 3; p++) {
        int d = p * 256 + lane * 4;
        unsigned short* xp = x16 + (size_t)n * DD + d;
        const float* hp = h + (size_t)n * DD + d;
        float o[4];
#pragma unroll
        for (int j = 0; j < 4; j++)
            o[j] = b2f(xp[j]) * la0 + hp[j] * la1;
#pragma unroll
        for (int j = 0; j < 4; j++) xp[j] = f2b_rne(o[j]);
        if (outf) {
            float4 ov = make_float4(o[0], o[1], o[2], o[3]);
            *reinterpret_cast<float4*>((float*)outf + (size_t)n * DD + d) = ov;
        }
    }
}

extern "C" void kernel_launch(void* const* d_in, const int* in_sizes, int n_in,
                              void* d_out, int out_size, void* d_ws, size_t ws_size,
                              hipStream_t stream)
{
    const int N = NN, E = EE;
    const float* x_in      = (const float*)d_in[0];
    const float* edge_attr = (const float*)d_in[1];
    const float* Wck = (const float*)d_in[2];
    const float* bck = (const float*)d_in[3];
    const float* Wq  = (const float*)d_in[4];
    const float* bq  = (const float*)d_in[5];
    const float* Wv  = (const float*)d_in[6];
    const float* bv  = (const float*)d_in[7];
    const float* Waw = (const float*)d_in[8];
    const float* baw = (const float*)d_in[9];
    const float* Wc  = (const float*)d_in[10];
    const float* bc  = (const float*)d_in[11];
    const float* Wlx = (const float*)d_in[12];
    const float* blx = (const float*)d_in[13];
    const float* Wla1 = (const float*)d_in[14];
    const float* bla1 = (const float*)d_in[15];
    const float* Wla2 = (const float*)d_in[16];
    const float* bla2 = (const float*)d_in[17];
    const int* eidx = (const int*)d_in[18];
    const int* srcp = eidx;       // edge_index[0]
    const int* dstp = eidx + E;   // edge_index[1]

    float* p = (float*)d_ws;
    const size_t NB = (size_t)N * DD;   // 15.36M
    float* hbuf  = p; p += NB;
    float* abuf  = p; p += (size_t)E * HH;
    float* degf  = p; p += N;
    float* wfx32 = p; p += (size_t)DD * DD;
    float* bfbuf = p; p += DD;
    float* bqkvb = p; p += 3 * DD;
    // int region
    int* rowptr = (int*)p;
    int* cursor = rowptr + (N + 1);
    int* perm   = cursor + N;
    int* src_s  = perm + E;
    int* dst_s  = src_s + E;
    p += (size_t)(2 * N + 1 + 3 * E + 63) / 64 * 64;
    // bf16 regions (counted in floats = elems/2)
    unsigned short* xb16  = (unsigned short*)p; p += NB / 2;
    unsigned short* hb16  = (unsigned short*)p; p += NB / 2;
    unsigned short* qkv16 = (unsigned short*)p; p += 3 * NB / 2;   // [N][2304]
    unsigned short* ea16  = (unsigned short*)p; p += (size_t)E * DD / 2;
    unsigned short* kea16 = (unsigned short*)p; p += (size_t)E * DD / 2;
    unsigned short* agg16 = kea16;                 // reuse after aw_a done
    unsigned short* gb16  = qkv16;                 // reuse after agg done
    // weights
    unsigned short* wqkvt  = (unsigned short*)p; p += (size_t)3 * DD * DD / 2; // [2304][768]
    unsigned short* wcktopt= (unsigned short*)p; p += (size_t)DD * DD / 2;
    unsigned short* wct    = (unsigned short*)p; p += (size_t)DD * DD / 2;
    unsigned short* wla1tt = (unsigned short*)p; p += (size_t)DD * DD / 2;
    unsigned short* wst3   = (unsigned short*)p; p += (size_t)DD * 2 * DD / 2; // [768][1536]
    unsigned short* wlx16  = (unsigned short*)p; p += (size_t)DD * DD / 2;

    // ---- setup (once) ----
    hipMemsetAsync(cursor, 0, N * sizeof(int), stream);
    deg_kernel<<<(E + 255) / 256, 256, 0, stream>>>(dstp, cursor);
    scan_kernel<<<1, 256, 0, stream>>>(cursor, rowptr, cursor);
    fill_perm<<<(E + 255) / 256, 256, 0, stream>>>(srcp, dstp, cursor, perm, src_s, dst_s);
    degf_kernel<<<(N + 255) / 256, 256, 0, stream>>>(rowptr, degf);
    f2b_gather<<<(E * 96 + 255) / 256, 256, 0, stream>>>(edge_attr, perm, ea16);
    f2b_kernel<<<(N * 96 + 255) / 256, 256, 0, stream>>>(x_in, xb16, N * 96);

    for (int l = 0; l < NL; l++) {
        const float* Wck_l = Wck + (size_t)l * 2 * DD * DD;
        const float* bck_l = bck + (size_t)l * DD;
        const float* Wq_l  = Wq  + (size_t)l * DD * DD;
        const float* bq_l  = bq  + (size_t)l * DD;
        const float* Wv_l  = Wv  + (size_t)l * DD * DD;
        const float* bv_l  = bv  + (size_t)l * DD;
        const float* Waw_l = Waw + (size_t)l * HH * HH;
        const float* baw_l = baw + (size_t)l * HH;
        const float* Wc_l  = Wc  + (size_t)l * DD * DD;
        const float* bc_l  = bc  + (size_t)l * DD;
        const float* Wlx_l = Wlx + (size_t)l * DD * DD;
        const float* blx_l = blx + (size_t)l * DD;
        const float* Wla1_l = Wla1 + (size_t)l * 2 * DD * DD;
        const float* bla1_l = bla1 + (size_t)l * DD;
        const float* Wla2_l = Wla2 + (size_t)l * DD * 2;
        const float* bla2_l = bla2 + (size_t)l * 2;

        // ---- weight prep ----
        dim3 gt(DD / 32, DD / 32);
        transpose_w<<<gt, 256, 0, stream>>>(Wq_l, wqkvt, DD, DD, 0);
        transpose_w<<<gt, 256, 0, stream>>>(Wck_l + (size_t)DD * DD, wqkvt + (size_t)DD * DD, DD, DD, 0);
        transpose_w<<<gt, 256, 0, stream>>>(Wv_l, wqkvt + (size_t)2 * DD * DD, DD, DD, 0);
        transpose_w<<<gt, 256, 0, stream>>>(Wck_l, wcktopt, DD, DD, 0);
        transpose_w<<<gt, 256, 0, stream>>>(Wc_l, wct, DD, DD, 0);
        transpose_w<<<gt, 256, 0, stream>>>(Wla1_l, wla1tt, DD, DD, 0);
        transpose_w<<<gt, 256, 0, stream>>>(Wla1_l + (size_t)DD * DD, wst3, DD, 2 * DD, DD);
        f2b_kernel<<<(DD * 96 + 255) / 256, 256, 0, stream>>>(Wlx_l, wlx16, DD * 96);
        gemm_mfma<<<dim3(6, 6), 256, 0, stream>>>(wlx16, nullptr, wla1tt, nullptr, nullptr,
                                                  wfx32, nullptr, DD, DD, DD);
        transpose_w<<<gt, 256, 0, stream>>>(wfx32, wst3, DD, 2 * DD, 0);
        biasf_kernel<<<3, 256, 0, stream>>>(blx_l, Wla1_l, bla1_l, bfbuf);
        biasqkv_kernel<<<9, 256, 0, stream>>>(bq_l, bv_l, bqkvb);

        // ---- qkv node GEMM [N][2304] ----
        gemm_mfma<<<dim3(18, (N + 127) / 128), 256, 0, stream>>>(
            xb16, nullptr, wqkvt, bqkvb, nullptr, nullptr, qkv16, N, DD, 3 * DD);
        // ---- kea edge GEMM [E][768] ----
        gemm_mfma<<<dim3(6, (E + 127) / 128), 256, 0, stream>>>(
            ea16, nullptr, wcktopt, bck_l, nullptr, nullptr, kea16, E, DD, DD);
        // ---- attention coefficients ----
        aw_a_sorted<<<(E + 255) / 256, 256, 0, stream>>>(kea16, qkv16, Waw_l, baw_l,
                                                         src_s, dst_s, abuf);
        // ---- segmented weighted sum (normalization folded in) ----
        agg_kernel<<<N, 256, 0, stream>>>(qkv16, abuf, rowptr, src_s, agg16);
        // ---- h = agg @ Wc + deg*bc (dual fp32+bf16 out) ----
        gemm_mfma<<<dim3(6, (N + 127) / 128), 256, 0, stream>>>(
            agg16, nullptr, wct, bc_l, degf, hbuf, hb16, N, DD, DD);
        // ---- g = x@Wfx + h@Wla1_bot + bf ----
        gemm_mfma<<<dim3(6, (N + 127) / 128), 256, 0, stream>>>(
            xb16, hb16, wst3, bfbuf, nullptr, nullptr, gb16, N, 2 * DD, DD);
        // ---- gated combine ----
        combine_kernel<<<(N + 3) / 4, 256, 0, stream>>>(
            gb16, Wla2_l, bla2_l, xb16, hbuf,
            (l == NL - 1) ? (float*)d_out : nullptr, N);
    }
}

// Round 8
// 2301.717 us; speedup vs baseline: 11.9531x; 1.0455x over previous
//
#include <hip/hip_runtime.h>
#include <hip/hip_bf16.h>
#include <math.h>

#define DD 768
#define HH 8
#define DHH 96
#define NL 3
#define NN 20000
#define EE 100000

typedef __attribute__((ext_vector_type(8))) __bf16 bf16x8;
typedef __attribute__((ext_vector_type(4))) float f32x4;
typedef __attribute__((ext_vector_type(8))) unsigned short u16x8;

__host__ __device__ static inline int imin(int a, int b) { return a < b ? a : b; }

__device__ inline float b2f(unsigned short u) {
    union { unsigned int v; float f; } x; x.v = ((unsigned int)u) << 16; return x.f;
}
__device__ inline unsigned short f2b_rne(float f) {
    union { float f; unsigned int v; } x; x.f = f;
    unsigned int v = x.v;
    return (unsigned short)((v + 0x7FFFu + ((v >> 16) & 1u)) >> 16);
}

// ================= CSR build =================
__global__ void deg_kernel(const int* __restrict__ dst, int* __restrict__ cnt)
{
    int i = blockIdx.x * 256 + threadIdx.x;
    if (i < EE) atomicAdd(&cnt[dst[i]], 1);
}

__global__ __launch_bounds__(256)
void scan_kernel(const int* __restrict__ deg, int* __restrict__ rowptr, int* __restrict__ cursor)
{
    __shared__ int part[256];
    int t = threadIdx.x;
    const int per = (NN + 255) / 256;
    int lo = t * per, hi = imin(NN, lo + per);
    int s = 0;
    for (int i = lo; i < hi; i++) s += deg[i];
    part[t] = s;
    __syncthreads();
    if (t == 0) {
        int acc = 0;
        for (int i = 0; i < 256; i++) { int v = part[i]; part[i] = acc; acc += v; }
        rowptr[NN] = acc;
    }
    __syncthreads();
    int run = part[t];
    for (int i = lo; i < hi; i++) {
        rowptr[i] = run; cursor[i] = run;
        run += deg[i];
    }
}

__global__ void fill_perm(const int* __restrict__ src, const int* __restrict__ dst,
                          int* __restrict__ cursor, int* __restrict__ perm,
                          int* __restrict__ src_s, int* __restrict__ dst_s)
{
    int e = blockIdx.x * 256 + threadIdx.x;
    if (e >= EE) return;
    int d = dst[e];
    int pos = atomicAdd(&cursor[d], 1);
    perm[pos] = e;
    src_s[pos] = src[e];
    dst_s[pos] = d;
}

__global__ void degf_kernel(const int* __restrict__ rowptr, float* __restrict__ degf)
{
    int n = blockIdx.x * 256 + threadIdx.x;
    if (n < NN) degf[n] = (float)(rowptr[n + 1] - rowptr[n]);
}

// ================= conversions =================
__global__ void f2b_kernel(const float* __restrict__ in, unsigned short* __restrict__ out, int n8)
{
    int i = blockIdx.x * 256 + threadIdx.x;
    if (i >= n8) return;
    const float4* p = reinterpret_cast<const float4*>(in + (size_t)i * 8);
    float4 a = p[0], b = p[1];
    u16x8 o;
    o[0] = f2b_rne(a.x); o[1] = f2b_rne(a.y); o[2] = f2b_rne(a.z); o[3] = f2b_rne(a.w);
    o[4] = f2b_rne(b.x); o[5] = f2b_rne(b.y); o[6] = f2b_rne(b.z); o[7] = f2b_rne(b.w);
    *reinterpret_cast<u16x8*>(out + (size_t)i * 8) = o;
}

__global__ void f2b_gather(const float* __restrict__ in, const int* __restrict__ perm,
                           unsigned short* __restrict__ out)
{
    int i = blockIdx.x * 256 + threadIdx.x;
    if (i >= EE * 96) return;
    int m = i / 96;
    int d8 = (i % 96) * 8;
    int row = perm[m];
    const float4* p = reinterpret_cast<const float4*>(in + (size_t)row * DD + d8);
    float4 a = p[0], b = p[1];
    u16x8 o;
    o[0] = f2b_rne(a.x); o[1] = f2b_rne(a.y); o[2] = f2b_rne(a.z); o[3] = f2b_rne(a.w);
    o[4] = f2b_rne(b.x); o[5] = f2b_rne(b.y); o[6] = f2b_rne(b.z); o[7] = f2b_rne(b.w);
    *reinterpret_cast<u16x8*>(out + (size_t)m * DD + d8) = o;
}

// ---- W [Kin][768] fp32 (row stride 768) -> Wt[n*out_ld + out_off + k] bf16 ----
__global__ void transpose_w(const float* __restrict__ W, unsigned short* __restrict__ Wt,
                            int Kin, int out_ld, int out_off)
{
    __shared__ float tile[32][33];
    int kb = blockIdx.x * 32, nb = blockIdx.y * 32;
    int tx = threadIdx.x & 31, ty = threadIdx.x >> 5;
#pragma unroll
    for (int i = 0; i < 32; i += 8)
        tile[ty + i][tx] = W[(size_t)(kb + ty + i) * DD + nb + tx];
    __syncthreads();
#pragma unroll
    for (int i = 0; i < 32; i += 8)
        Wt[(size_t)(nb + ty + i) * out_ld + out_off + kb + tx] = f2b_rne(tile[tx][ty + i]);
}

__global__ void biasf_kernel(const float* __restrict__ blx, const float* __restrict__ Wla1,
                             const float* __restrict__ bla1, float* __restrict__ bf)
{
    int n = blockIdx.x * 256 + threadIdx.x;
    if (n >= DD) return;
    float s = bla1[n];
    for (int k = 0; k < DD; k++) s += blx[k] * Wla1[(size_t)k * DD + n];
    bf[n] = s;
}

__global__ void biasqkv_kernel(const float* __restrict__ bq, const float* __restrict__ bv,
                               float* __restrict__ bqkv)
{
    int i = blockIdx.x * 256 + threadIdx.x;
    if (i >= 3 * DD) return;
    float v = 0.f;
    if (i < DD) v = bq[i];
    else if (i >= 2 * DD) v = bv[i - 2 * DD];
    bqkv[i] = v;
}

// ================= MFMA GEMM =================
// C[M,Nw] = concat(A0,A1)[M,K] @ W + bias*rowscale ; Wt [Nw][K] bf16 n-major.
// 256x128 tile, 8 waves (4m x 2n), BK=64. XCD-chunked bijective swizzle.
// bf16 C via padded-LDS staging (stride 136) in two 128-row halves.
__global__ __launch_bounds__(512, 4)
void gemm_mfma(const unsigned short* __restrict__ A0,
               const unsigned short* __restrict__ A1,
               const unsigned short* __restrict__ Wt,
               const float* __restrict__ bias,
               const float* __restrict__ rowscale,
               float* __restrict__ C32,
               unsigned short* __restrict__ C16,
               int M, int K, int Nw)
{
    __shared__ __align__(16) char smem[49152];   // As 32KB + Bs 16KB
    char* As = smem;
    char* Bs = smem + 32768;
    const int t = threadIdx.x;
    const int l = t & 63;
    const int w = t >> 6;            // wave 0..7
    const int wm = w & 3, wn = w >> 2;

    // ---- XCD-chunked bijective swizzle (m204) ----
    const int gx = gridDim.x;
    const int nwg = gx * gridDim.y;
    const int lin = blockIdx.y * gx + blockIdx.x;
    const int xcd = lin & 7, pos = lin >> 3;
    const int q8 = nwg >> 3, r8 = nwg & 7;
    const int base = (xcd < r8) ? xcd * (q8 + 1) : r8 * (q8 + 1) + (xcd - r8) * q8;
    const int swz = base + pos;
    const int bn = swz % gx, bm = swz / gx;

    const int srow = t >> 3;                      // 0..63
    const int ssrc = ((t & 7) ^ (srow & 7)) * 8;  // swizzled source col (bf16)

    const int lane_r = l & 15;
    const int lane_k = l >> 4;

    f32x4 acc[4][4];
#pragma unroll
    for (int m = 0; m < 4; m++)
#pragma unroll
        for (int n = 0; n < 4; n++) acc[m][n] = (f32x4){0.f, 0.f, 0.f, 0.f};

    for (int k0 = 0; k0 < K; k0 += 64) {
        const unsigned short* Ap; int kbase;
        if (k0 < DD) { Ap = A0; kbase = k0; }
        else         { Ap = A1; kbase = k0 - DD; }
        // ---- A tile: 256 rows x 64k, 4 stripes of 64 rows ----
#pragma unroll
        for (int i = 0; i < 4; i++) {
            int grow = bm * 256 + i * 64 + srow;
            char* ldstA = As + ((i * 64 + w * 8) << 7);
            if (grow < M) {
                const unsigned short* g = Ap + (size_t)grow * DD + kbase + ssrc;
                __builtin_amdgcn_global_load_lds(
                    (const __attribute__((address_space(1))) void*)g,
                    (__attribute__((address_space(3))) void*)ldstA, 16, 0, 0);
            }
        }
        // ---- B tile: 128 rows x 64k, 2 stripes ----
#pragma unroll
        for (int i = 0; i < 2; i++) {
            int gn = bn * 128 + i * 64 + srow;
            const unsigned short* gB = Wt + (size_t)gn * K + k0 + ssrc;
            char* ldstB = Bs + ((i * 64 + w * 8) << 7);
            __builtin_amdgcn_global_load_lds(
                (const __attribute__((address_space(1))) void*)gB,
                (__attribute__((address_space(3))) void*)ldstB, 16, 0, 0);
        }
        __syncthreads();
#pragma unroll
        for (int kk = 0; kk < 2; kk++) {
            bf16x8 af[4], bfr[4];
#pragma unroll
            for (int m = 0; m < 4; m++) {
                int r = wm * 64 + m * 16 + lane_r;
                int slot = (kk * 4 + lane_k) ^ (r & 7);
                af[m] = *reinterpret_cast<const bf16x8*>(As + r * 128 + slot * 16);
            }
#pragma unroll
            for (int n = 0; n < 4; n++) {
                int r = wn * 64 + n * 16 + lane_r;
                int slot = (kk * 4 + lane_k) ^ (r & 7);
                bfr[n] = *reinterpret_cast<const bf16x8*>(Bs + r * 128 + slot * 16);
            }
#pragma unroll
            for (int m = 0; m < 4; m++)
#pragma unroll
                for (int n = 0; n < 4; n++)
                    acc[m][n] = __builtin_amdgcn_mfma_f32_16x16x32_bf16(
                        af[m], bfr[n], acc[m][n], 0, 0, 0);
        }
        __syncthreads();
    }

    // ---- fp32 direct path (h-GEMM / wfx) ----
    if (C32) {
#pragma unroll
        for (int n = 0; n < 4; n++) {
            int col = bn * 128 + wn * 64 + n * 16 + lane_r;
            float badd = bias ? bias[col] : 0.f;
#pragma unroll
            for (int m = 0; m < 4; m++) {
#pragma unroll
                for (int j = 0; j < 4; j++) {
                    int r = bm * 256 + wm * 64 + m * 16 + lane_k * 4 + j;
                    if (r < M) {
                        float bs = rowscale ? rowscale[r] : 1.f;
                        C32[(size_t)r * Nw + col] = acc[m][n][j] + badd * bs;
                    }
                }
            }
        }
    }
    // ---- bf16 path via padded LDS staging, two 128-row halves ----
    if (C16) {
        unsigned short* cs = (unsigned short*)smem;   // stride 136 bf16 (272B rows)
#pragma unroll
        for (int half = 0; half < 2; half++) {
            __syncthreads();
            if ((wm >> 1) == half) {
#pragma unroll
                for (int n = 0; n < 4; n++) {
                    int lcol = wn * 64 + n * 16 + lane_r;
                    float badd = bias ? bias[bn * 128 + lcol] : 0.f;
#pragma unroll
                    for (int m = 0; m < 4; m++) {
#pragma unroll
                        for (int j = 0; j < 4; j++) {
                            int lr = (wm & 1) * 64 + m * 16 + lane_k * 4 + j;
                            int r = bm * 256 + half * 128 + lr;
                            float bs = rowscale ? (r < M ? rowscale[r] : 0.f) : 1.f;
                            cs[lr * 136 + lcol] = f2b_rne(acc[m][n][j] + badd * bs);
                        }
                    }
                }
            }
            __syncthreads();
            int rr = t >> 2, qd = (t & 3) * 32;      // 4 threads/row, 32 cols each
            int grow = bm * 256 + half * 128 + rr;
            if (grow < M) {
                u16x8* dst = reinterpret_cast<u16x8*>(C16 + (size_t)grow * Nw + bn * 128 + qd);
                const u16x8* s = reinterpret_cast<const u16x8*>(cs + rr * 136 + qd);
                dst[0] = s[0];
                dst[1] = s[1];
                dst[2] = s[2];
                dst[3] = s[3];
            }
        }
    }
}

// ================= edge attention =================
__global__ __launch_bounds__(256)
void aw_a_sorted(const unsigned short* __restrict__ kea,
                 const unsigned short* __restrict__ qkv,
                 const float* __restrict__ Waw, const float* __restrict__ baw,
                 const int* __restrict__ src_s, const int* __restrict__ dst_s,
                 float* __restrict__ abuf)
{
    int j = blockIdx.x * 256 + threadIdx.x;
    if (j >= EE) return;
    const u16x8* ke = reinterpret_cast<const u16x8*>(kea + (size_t)j * DD);
    const u16x8* kr = reinterpret_cast<const u16x8*>(qkv + (size_t)src_s[j] * (3 * DD) + DD);
    const u16x8* qr = reinterpret_cast<const u16x8*>(qkv + (size_t)dst_s[j] * (3 * DD));
    constexpr float rs = 0.03608439182435161f; // 1/sqrt(768)
    float t[HH];
#pragma unroll
    for (int h = 0; h < HH; h++) {
        float s = 0.f;
#pragma unroll
        for (int c = 0; c < 12; c++) {
            u16x8 qv = qr[h * 12 + c];
            u16x8 k1 = ke[h * 12 + c];
            u16x8 k2 = kr[h * 12 + c];
#pragma unroll
            for (int x = 0; x < 8; x++)
                s = fmaf(b2f(qv[x]), b2f(k1[x]) + b2f(k2[x]), s);
        }
        float aw = s * rs;
        t[h] = aw > 0.f ? aw : 0.2f * aw;
    }
#pragma unroll
    for (int h = 0; h < HH; h++) {
        float z = baw[h];
#pragma unroll
        for (int h2 = 0; h2 < HH; h2++) z = fmaf(t[h2], Waw[h2 * HH + h], z);
        abuf[(size_t)j * HH + h] = expf(z);
    }
}

// agg[n] = (sum_j a_j (*) v[src_j]) / sc[n]  — one block per node
__global__ __launch_bounds__(256)
void agg_kernel(const unsigned short* __restrict__ qkv, const float* __restrict__ abuf,
                const int* __restrict__ rowptr, const int* __restrict__ src_s,
                unsigned short* __restrict__ agg)
{
    __shared__ float inv8[HH];
    int n = blockIdx.x;
    int jlo = rowptr[n], jhi = rowptr[n + 1];
    int t = threadIdx.x;
    if (t < HH) {
        float s = 0.f;
        for (int j = jlo; j < jhi; j++) s += abuf[(size_t)j * HH + t];
        inv8[t] = (s == 0.f) ? 1.f : 1.f / s;
    }
    __syncthreads();
    int c0 = t, c1 = t + 256, c2 = t + 512;
    int h0 = c0 / DHH, h1 = c1 / DHH, h2 = c2 / DHH;
    float a0 = 0.f, a1 = 0.f, a2 = 0.f;
    for (int j = jlo; j < jhi; j++) {
        const unsigned short* v = qkv + (size_t)src_s[j] * (3 * DD) + 2 * DD;
        const float* ab = abuf + (size_t)j * HH;
        a0 = fmaf(ab[h0], b2f(v[c0]), a0);
        a1 = fmaf(ab[h1], b2f(v[c1]), a1);
        a2 = fmaf(ab[h2], b2f(v[c2]), a2);
    }
    unsigned short* o = agg + (size_t)n * DD;
    o[c0] = f2b_rne(a0 * inv8[h0]);
    o[c1] = f2b_rne(a1 * inv8[h1]);
    o[c2] = f2b_rne(a2 * inv8[h2]);
}

// one wave per node: z = lrelu(g)@Wla2 + bla2 ; la = softmax(z) ; out = x*la0 + h*la1
__global__ __launch_bounds__(256)
void combine_kernel(const unsigned short* __restrict__ g, const float* __restrict__ Wla2,
                    const float* __restrict__ bla2, unsigned short* __restrict__ x16,
                    const float* __restrict__ h, float* __restrict__ outf, int Nn)
{
    int w = threadIdx.x >> 6;
    int lane = threadIdx.x & 63;
    int n = blockIdx.x * 4 + w;
    if (n >= Nn) return;
    float z0 = 0.f, z1 = 0.f;
#pragma unroll
    for (int p = 0; p < 3; p++) {
        int d = p * 256 + lane * 4;
        const unsigned short* gp = g + (size_t)n * DD + d;
#pragma unroll
        for (int j = 0; j < 4; j++) {
            float gv = b2f(gp[j]);
            float tt = gv > 0.f ? gv : 0.2f * gv;
            z0 = fmaf(tt, Wla2[(d + j) * 2 + 0], z0);
            z1 = fmaf(tt, Wla2[(d + j) * 2 + 1], z1);
        }
    }
#pragma unroll
    for (int off = 32; off > 0; off >>= 1) {
        z0 += __shfl_xor(z0, off);
        z1 += __shfl_xor(z1, off);
    }
    z0 += bla2[0]; z1 += bla2[1];
    float mx = fmaxf(z0, z1);
    float e0v = expf(z0 - mx), e1v = expf(z1 - mx);
    float inv = 1.f / (e0v + e1v);
    float la0 = e0v * inv, la1 = e1v * inv;
#pragma unroll
    for (int p = 0; p < 3; p++) {
        int d = p * 256 + lane * 4;
        unsigned short* xp = x16 + (size_t)n * DD + d;
        const float* hp = h + (size_t)n * DD + d;
        float o[4];
#pragma unroll
        for (int j = 0; j < 4; j++)
            o[j] = b2f(xp[j]) * la0 + hp[j] * la1;
#pragma unroll
        for (int j = 0; j < 4; j++) xp[j] = f2b_rne(o[j]);
        if (outf) {
            float4 ov = make_float4(o[0], o[1], o[2], o[3]);
            *reinterpret_cast<float4*>((float*)outf + (size_t)n * DD + d) = ov;
        }
    }
}

extern "C" void kernel_launch(void* const* d_in, const int* in_sizes, int n_in,
                              void* d_out, int out_size, void* d_ws, size_t ws_size,
                              hipStream_t stream)
{
    const int N = NN, E = EE;
    const float* x_in      = (const float*)d_in[0];
    const float* edge_attr = (const float*)d_in[1];
    const float* Wck = (const float*)d_in[2];
    const float* bck = (const float*)d_in[3];
    const float* Wq  = (const float*)d_in[4];
    const float* bq  = (const float*)d_in[5];
    const float* Wv  = (const float*)d_in[6];
    const float* bv  = (const float*)d_in[7];
    const float* Waw = (const float*)d_in[8];
    const float* baw = (const float*)d_in[9];
    const float* Wc  = (const float*)d_in[10];
    const float* bc  = (const float*)d_in[11];
    const float* Wlx = (const float*)d_in[12];
    const float* blx = (const float*)d_in[13];
    const float* Wla1 = (const float*)d_in[14];
    const float* bla1 = (const float*)d_in[15];
    const float* Wla2 = (const float*)d_in[16];
    const float* bla2 = (const float*)d_in[17];
    const int* eidx = (const int*)d_in[18];
    const int* srcp = eidx;       // edge_index[0]
    const int* dstp = eidx + E;   // edge_index[1]

    float* p = (float*)d_ws;
    const size_t NB = (size_t)N * DD;   // 15.36M
    float* hbuf  = p; p += NB;
    float* abuf  = p; p += (size_t)E * HH;
    float* degf  = p; p += N;
    float* wfx32 = p; p += (size_t)DD * DD;
    float* bfbuf = p; p += DD;
    float* bqkvb = p; p += 3 * DD;
    // int region
    int* rowptr = (int*)p;
    int* cursor = rowptr + (N + 1);
    int* perm   = cursor + N;
    int* src_s  = perm + E;
    int* dst_s  = src_s + E;
    p += (size_t)(2 * N + 1 + 3 * E + 63) / 64 * 64;
    // bf16 regions (counted in floats = elems/2)
    unsigned short* xb16  = (unsigned short*)p; p += NB / 2;
    unsigned short* hb16  = (unsigned short*)p; p += NB / 2;
    unsigned short* qkv16 = (unsigned short*)p; p += 3 * NB / 2;   // [N][2304]
    unsigned short* ea16  = (unsigned short*)p; p += (size_t)E * DD / 2;
    unsigned short* kea16 = (unsigned short*)p; p += (size_t)E * DD / 2;
    unsigned short* agg16 = kea16;                 // reuse after aw_a done
    unsigned short* gb16  = qkv16;                 // reuse after agg done
    // weights
    unsigned short* wqkvt  = (unsigned short*)p; p += (size_t)3 * DD * DD / 2; // [2304][768]
    unsigned short* wcktopt= (unsigned short*)p; p += (size_t)DD * DD / 2;
    unsigned short* wct    = (unsigned short*)p; p += (size_t)DD * DD / 2;
    unsigned short* wla1tt = (unsigned short*)p; p += (size_t)DD * DD / 2;
    unsigned short* wst3   = (unsigned short*)p; p += (size_t)DD * 2 * DD / 2; // [768][1536]
    unsigned short* wlx16  = (unsigned short*)p; p += (size_t)DD * DD / 2;

    // ---- setup (once) ----
    hipMemsetAsync(cursor, 0, N * sizeof(int), stream);
    deg_kernel<<<(E + 255) / 256, 256, 0, stream>>>(dstp, cursor);
    scan_kernel<<<1, 256, 0, stream>>>(cursor, rowptr, cursor);
    fill_perm<<<(E + 255) / 256, 256, 0, stream>>>(srcp, dstp, cursor, perm, src_s, dst_s);
    degf_kernel<<<(N + 255) / 256, 256, 0, stream>>>(rowptr, degf);
    f2b_gather<<<(E * 96 + 255) / 256, 256, 0, stream>>>(edge_attr, perm, ea16);
    f2b_kernel<<<(N * 96 + 255) / 256, 256, 0, stream>>>(x_in, xb16, N * 96);

    for (int l = 0; l < NL; l++) {
        const float* Wck_l = Wck + (size_t)l * 2 * DD * DD;
        const float* bck_l = bck + (size_t)l * DD;
        const float* Wq_l  = Wq  + (size_t)l * DD * DD;
        const float* bq_l  = bq  + (size_t)l * DD;
        const float* Wv_l  = Wv  + (size_t)l * DD * DD;
        const float* bv_l  = bv  + (size_t)l * DD;
        const float* Waw_l = Waw + (size_t)l * HH * HH;
        const float* baw_l = baw + (size_t)l * HH;
        const float* Wc_l  = Wc  + (size_t)l * DD * DD;
        const float* bc_l  = bc  + (size_t)l * DD;
        const float* Wlx_l = Wlx + (size_t)l * DD * DD;
        const float* blx_l = blx + (size_t)l * DD;
        const float* Wla1_l = Wla1 + (size_t)l * 2 * DD * DD;
        const float* bla1_l = bla1 + (size_t)l * DD;
        const float* Wla2_l = Wla2 + (size_t)l * DD * 2;
        const float* bla2_l = bla2 + (size_t)l * 2;

        // ---- weight prep ----
        dim3 gt(DD / 32, DD / 32);
        transpose_w<<<gt, 256, 0, stream>>>(Wq_l, wqkvt, DD, DD, 0);
        transpose_w<<<gt, 256, 0, stream>>>(Wck_l + (size_t)DD * DD, wqkvt + (size_t)DD * DD, DD, DD, 0);
        transpose_w<<<gt, 256, 0, stream>>>(Wv_l, wqkvt + (size_t)2 * DD * DD, DD, DD, 0);
        transpose_w<<<gt, 256, 0, stream>>>(Wck_l, wcktopt, DD, DD, 0);
        transpose_w<<<gt, 256, 0, stream>>>(Wc_l, wct, DD, DD, 0);
        transpose_w<<<gt, 256, 0, stream>>>(Wla1_l, wla1tt, DD, DD, 0);
        transpose_w<<<gt, 256, 0, stream>>>(Wla1_l + (size_t)DD * DD, wst3, DD, 2 * DD, DD);
        f2b_kernel<<<(DD * 96 + 255) / 256, 256, 0, stream>>>(Wlx_l, wlx16, DD * 96);
        gemm_mfma<<<dim3(6, 3), 512, 0, stream>>>(wlx16, nullptr, wla1tt, nullptr, nullptr,
                                                  wfx32, nullptr, DD, DD, DD);
        transpose_w<<<gt, 256, 0, stream>>>(wfx32, wst3, DD, 2 * DD, 0);
        biasf_kernel<<<3, 256, 0, stream>>>(blx_l, Wla1_l, bla1_l, bfbuf);
        biasqkv_kernel<<<9, 256, 0, stream>>>(bq_l, bv_l, bqkvb);

        // ---- qkv node GEMM [N][2304] ----
        gemm_mfma<<<dim3(18, (N + 255) / 256), 512, 0, stream>>>(
            xb16, nullptr, wqkvt, bqkvb, nullptr, nullptr, qkv16, N, DD, 3 * DD);
        // ---- kea edge GEMM [E][768] ----
        gemm_mfma<<<dim3(6, (E + 255) / 256), 512, 0, stream>>>(
            ea16, nullptr, wcktopt, bck_l, nullptr, nullptr, kea16, E, DD, DD);
        // ---- attention coefficients ----
        aw_a_sorted<<<(E + 255) / 256, 256, 0, stream>>>(kea16, qkv16, Waw_l, baw_l,
                                                         src_s, dst_s, abuf);
        // ---- segmented weighted sum (normalization folded in) ----
        agg_kernel<<<N, 256, 0, stream>>>(qkv16, abuf, rowptr, src_s, agg16);
        // ---- h = agg @ Wc + deg*bc (dual fp32+bf16 out) ----
        gemm_mfma<<<dim3(6, (N + 255) / 256), 512, 0, stream>>>(
            agg16, nullptr, wct, bc_l, degf, hbuf, hb16, N, DD, DD);
        // ---- g = x@Wfx + h@Wla1_bot + bf ----
        gemm_mfma<<<dim3(6, (N + 255) / 256), 512, 0, stream>>>(
            xb16, hb16, wst3, bfbuf, nullptr, nullptr, gb16, N, 2 * DD, DD);
        // ---- gated combine ----
        combine_kernel<<<(N + 3) / 4, 256, 0, stream>>>(
            gb16, Wla2_l, bla2_l, xb16, hbuf,
            (l == NL - 1) ? (float*)d_out : nullptr, N);
    }
}

// Round 9
// 1776.076 us; speedup vs baseline: 15.4907x; 1.2960x over previous
//
#include <hip/hip_runtime.h>
#include <hip/hip_bf16.h>
#include <math.h>

#define DD 768
#define HH 8
#define DHH 96
#define NL 3
#define NN 20000
#define EE 100000

typedef __attribute__((ext_vector_type(8))) __bf16 bf16x8;
typedef __attribute__((ext_vector_type(4))) float f32x4;
typedef __attribute__((ext_vector_type(8))) unsigned short u16x8;

__host__ __device__ static inline int imin(int a, int b) { return a < b ? a : b; }

__device__ inline float b2f(unsigned short u) {
    union { unsigned int v; float f; } x; x.v = ((unsigned int)u) << 16; return x.f;
}
__device__ inline unsigned short f2b_rne(float f) {
    union { float f; unsigned int v; } x; x.f = f;
    unsigned int v = x.v;
    return (unsigned short)((v + 0x7FFFu + ((v >> 16) & 1u)) >> 16);
}
// unpack dword -> two bf16 floats (elem order: low half = lower address)
__device__ inline void b2f2(unsigned int u, float& lo, float& hi) {
    union { unsigned int v; float f; } x;
    x.v = u << 16; lo = x.f;
    x.v = u & 0xffff0000u; hi = x.f;
}
__device__ inline unsigned int packbf(float a, float b) {
    return (unsigned int)f2b_rne(a) | ((unsigned int)f2b_rne(b) << 16);
}

// ================= CSR build =================
__global__ void deg_kernel(const int* __restrict__ dst, int* __restrict__ cnt)
{
    int i = blockIdx.x * 256 + threadIdx.x;
    if (i < EE) atomicAdd(&cnt[dst[i]], 1);
}

__global__ __launch_bounds__(256)
void scan_kernel(const int* __restrict__ deg, int* __restrict__ rowptr, int* __restrict__ cursor)
{
    __shared__ int part[256];
    int t = threadIdx.x;
    const int per = (NN + 255) / 256;
    int lo = t * per, hi = imin(NN, lo + per);
    int s = 0;
    for (int i = lo; i < hi; i++) s += deg[i];
    part[t] = s;
    __syncthreads();
    if (t == 0) {
        int acc = 0;
        for (int i = 0; i < 256; i++) { int v = part[i]; part[i] = acc; acc += v; }
        rowptr[NN] = acc;
    }
    __syncthreads();
    int run = part[t];
    for (int i = lo; i < hi; i++) {
        rowptr[i] = run; cursor[i] = run;
        run += deg[i];
    }
}

__global__ void fill_perm(const int* __restrict__ src, const int* __restrict__ dst,
                          int* __restrict__ cursor, int* __restrict__ perm,
                          int* __restrict__ src_s)
{
    int e = blockIdx.x * 256 + threadIdx.x;
    if (e >= EE) return;
    int d = dst[e];
    int pos = atomicAdd(&cursor[d], 1);
    perm[pos] = e;
    src_s[pos] = src[e];
}

__global__ void degf_kernel(const int* __restrict__ rowptr, float* __restrict__ degf)
{
    int n = blockIdx.x * 256 + threadIdx.x;
    if (n < NN) degf[n] = (float)(rowptr[n + 1] - rowptr[n]);
}

// ================= conversions =================
__global__ void f2b_kernel(const float* __restrict__ in, unsigned short* __restrict__ out, int n8)
{
    int i = blockIdx.x * 256 + threadIdx.x;
    if (i >= n8) return;
    const float4* p = reinterpret_cast<const float4*>(in + (size_t)i * 8);
    float4 a = p[0], b = p[1];
    u16x8 o;
    o[0] = f2b_rne(a.x); o[1] = f2b_rne(a.y); o[2] = f2b_rne(a.z); o[3] = f2b_rne(a.w);
    o[4] = f2b_rne(b.x); o[5] = f2b_rne(b.y); o[6] = f2b_rne(b.z); o[7] = f2b_rne(b.w);
    *reinterpret_cast<u16x8*>(out + (size_t)i * 8) = o;
}

__global__ void f2b_gather(const float* __restrict__ in, const int* __restrict__ perm,
                           unsigned short* __restrict__ out)
{
    int i = blockIdx.x * 256 + threadIdx.x;
    if (i >= EE * 96) return;
    int m = i / 96;
    int d8 = (i % 96) * 8;
    int row = perm[m];
    const float4* p = reinterpret_cast<const float4*>(in + (size_t)row * DD + d8);
    float4 a = p[0], b = p[1];
    u16x8 o;
    o[0] = f2b_rne(a.x); o[1] = f2b_rne(a.y); o[2] = f2b_rne(a.z); o[3] = f2b_rne(a.w);
    o[4] = f2b_rne(b.x); o[5] = f2b_rne(b.y); o[6] = f2b_rne(b.z); o[7] = f2b_rne(b.w);
    *reinterpret_cast<u16x8*>(out + (size_t)m * DD + d8) = o;
}

// ---- W [Kin][768] fp32 -> Wt[n*out_ld + out_off + k] bf16 ; z-batched ----
__global__ void transpose_w(const float* __restrict__ W, unsigned short* __restrict__ Wt,
                            int Kin, int out_ld, int out_off,
                            size_t strideW, size_t strideWt)
{
    __shared__ float tile[32][33];
    int z = blockIdx.z;
    W  += (size_t)z * strideW;
    Wt += (size_t)z * strideWt;
    int kb = blockIdx.x * 32, nb = blockIdx.y * 32;
    int tx = threadIdx.x & 31, ty = threadIdx.x >> 5;
#pragma unroll
    for (int i = 0; i < 32; i += 8)
        tile[ty + i][tx] = W[(size_t)(kb + ty + i) * DD + nb + tx];
    __syncthreads();
#pragma unroll
    for (int i = 0; i < 32; i += 8)
        Wt[(size_t)(nb + ty + i) * out_ld + out_off + kb + tx] = f2b_rne(tile[tx][ty + i]);
}

// bf[l][n] = bla1[l][n] + sum_k blx[l][k] * Wla1_top[l][k][n]   (grid: (3, NL))
__global__ void biasf_kernel(const float* __restrict__ blx, const float* __restrict__ Wla1,
                             const float* __restrict__ bla1, float* __restrict__ bf)
{
    int l = blockIdx.y;
    const float* blxl  = blx  + (size_t)l * DD;
    const float* Wla1l = Wla1 + (size_t)l * 2 * DD * DD;
    const float* bla1l = bla1 + (size_t)l * DD;
    float* bfl = bf + (size_t)l * DD;
    int n = blockIdx.x * 256 + threadIdx.x;
    if (n >= DD) return;
    float s = bla1l[n];
    for (int k = 0; k < DD; k++) s += blxl[k] * Wla1l[(size_t)k * DD + n];
    bfl[n] = s;
}

// grid (9, NL)
__global__ void biasqkv_kernel(const float* __restrict__ bq, const float* __restrict__ bv,
                               float* __restrict__ bqkv)
{
    int l = blockIdx.y;
    int i = blockIdx.x * 256 + threadIdx.x;
    if (i >= 3 * DD) return;
    float v = 0.f;
    if (i < DD) v = bq[(size_t)l * DD + i];
    else if (i >= 2 * DD) v = bv[(size_t)l * DD + i - 2 * DD];
    bqkv[(size_t)l * 3 * DD + i] = v;
}

// ================= MFMA GEMM =================
// C[M,Nw] = concat(A0,A1)[M,K] @ W + bias*rowscale ; Wt [Nw][K] bf16 n-major.
// 256x128 tile, 8 waves, BK=64, XCD-chunked bijective swizzle, z-batched.
__global__ __launch_bounds__(512, 4)
void gemm_mfma(const unsigned short* __restrict__ A0,
               const unsigned short* __restrict__ A1,
               const unsigned short* __restrict__ Wt,
               const float* __restrict__ bias,
               const float* __restrict__ rowscale,
               float* __restrict__ C32,
               unsigned short* __restrict__ C16,
               int M, int K, int Nw,
               size_t bsA, size_t bsW, size_t bsC)
{
    __shared__ __align__(16) char smem[49152];   // As 32KB + Bs 16KB
    char* As = smem;
    char* Bs = smem + 32768;
    const int z = blockIdx.z;
    A0 += (size_t)z * bsA;
    Wt += (size_t)z * bsW;
    if (C32) C32 += (size_t)z * bsC;
    if (C16) C16 += (size_t)z * bsC;
    const int t = threadIdx.x;
    const int l = t & 63;
    const int w = t >> 6;            // wave 0..7
    const int wm = w & 3, wn = w >> 2;

    // ---- XCD-chunked bijective swizzle (m204) ----
    const int gx = gridDim.x;
    const int nwg = gx * gridDim.y;
    const int lin = blockIdx.y * gx + blockIdx.x;
    const int xcd = lin & 7, pos = lin >> 3;
    const int q8 = nwg >> 3, r8 = nwg & 7;
    const int base = (xcd < r8) ? xcd * (q8 + 1) : r8 * (q8 + 1) + (xcd - r8) * q8;
    const int swz = base + pos;
    const int bn = swz % gx, bm = swz / gx;

    const int srow = t >> 3;                      // 0..63
    const int ssrc = ((t & 7) ^ (srow & 7)) * 8;  // swizzled source col (bf16)

    const int lane_r = l & 15;
    const int lane_k = l >> 4;

    f32x4 acc[4][4];
#pragma unroll
    for (int m = 0; m < 4; m++)
#pragma unroll
        for (int n = 0; n < 4; n++) acc[m][n] = (f32x4){0.f, 0.f, 0.f, 0.f};

    for (int k0 = 0; k0 < K; k0 += 64) {
        const unsigned short* Ap; int kbase;
        if (k0 < DD) { Ap = A0; kbase = k0; }
        else         { Ap = A1; kbase = k0 - DD; }
#pragma unroll
        for (int i = 0; i < 4; i++) {
            int grow = bm * 256 + i * 64 + srow;
            char* ldstA = As + ((i * 64 + w * 8) << 7);
            if (grow < M) {
                const unsigned short* g = Ap + (size_t)grow * DD + kbase + ssrc;
                __builtin_amdgcn_global_load_lds(
                    (const __attribute__((address_space(1))) void*)g,
                    (__attribute__((address_space(3))) void*)ldstA, 16, 0, 0);
            }
        }
#pragma unroll
        for (int i = 0; i < 2; i++) {
            int gn = bn * 128 + i * 64 + srow;
            const unsigned short* gB = Wt + (size_t)gn * K + k0 + ssrc;
            char* ldstB = Bs + ((i * 64 + w * 8) << 7);
            __builtin_amdgcn_global_load_lds(
                (const __attribute__((address_space(1))) void*)gB,
                (__attribute__((address_space(3))) void*)ldstB, 16, 0, 0);
        }
        __syncthreads();
#pragma unroll
        for (int kk = 0; kk < 2; kk++) {
            bf16x8 af[4], bfr[4];
#pragma unroll
            for (int m = 0; m < 4; m++) {
                int r = wm * 64 + m * 16 + lane_r;
                int slot = (kk * 4 + lane_k) ^ (r & 7);
                af[m] = *reinterpret_cast<const bf16x8*>(As + r * 128 + slot * 16);
            }
#pragma unroll
            for (int n = 0; n < 4; n++) {
                int r = wn * 64 + n * 16 + lane_r;
                int slot = (kk * 4 + lane_k) ^ (r & 7);
                bfr[n] = *reinterpret_cast<const bf16x8*>(Bs + r * 128 + slot * 16);
            }
#pragma unroll
            for (int m = 0; m < 4; m++)
#pragma unroll
                for (int n = 0; n < 4; n++)
                    acc[m][n] = __builtin_amdgcn_mfma_f32_16x16x32_bf16(
                        af[m], bfr[n], acc[m][n], 0, 0, 0);
        }
        __syncthreads();
    }

    // ---- fp32 direct path ----
    if (C32) {
#pragma unroll
        for (int n = 0; n < 4; n++) {
            int col = bn * 128 + wn * 64 + n * 16 + lane_r;
            float badd = bias ? bias[col] : 0.f;
#pragma unroll
            for (int m = 0; m < 4; m++) {
#pragma unroll
                for (int j = 0; j < 4; j++) {
                    int r = bm * 256 + wm * 64 + m * 16 + lane_k * 4 + j;
                    if (r < M) {
                        float bs = rowscale ? rowscale[r] : 1.f;
                        C32[(size_t)r * Nw + col] = acc[m][n][j] + badd * bs;
                    }
                }
            }
        }
    }
    // ---- bf16 path via padded LDS staging, two 128-row halves ----
    if (C16) {
        unsigned short* cs = (unsigned short*)smem;   // stride 136 bf16 (272B rows)
#pragma unroll
        for (int half = 0; half < 2; half++) {
            __syncthreads();
            if ((wm >> 1) == half) {
#pragma unroll
                for (int n = 0; n < 4; n++) {
                    int lcol = wn * 64 + n * 16 + lane_r;
                    float badd = bias ? bias[bn * 128 + lcol] : 0.f;
#pragma unroll
                    for (int m = 0; m < 4; m++) {
#pragma unroll
                        for (int j = 0; j < 4; j++) {
                            int lr = (wm & 1) * 64 + m * 16 + lane_k * 4 + j;
                            int r = bm * 256 + half * 128 + lr;
                            float bs = rowscale ? (r < M ? rowscale[r] : 0.f) : 1.f;
                            cs[lr * 136 + lcol] = f2b_rne(acc[m][n][j] + badd * bs);
                        }
                    }
                }
            }
            __syncthreads();
            int rr = t >> 2, qd = (t & 3) * 32;      // 4 threads/row, 32 cols each
            int grow = bm * 256 + half * 128 + rr;
            if (grow < M) {
                u16x8* dst = reinterpret_cast<u16x8*>(C16 + (size_t)grow * Nw + bn * 128 + qd);
                const u16x8* s = reinterpret_cast<const u16x8*>(cs + rr * 136 + qd);
                dst[0] = s[0];
                dst[1] = s[1];
                dst[2] = s[2];
                dst[3] = s[3];
            }
        }
    }
}

// ================= fused edge attention + aggregation =================
// one block (128 thr) per node: for each incoming edge j:
//   aw[h] = q[n]_h . (kea[j]_h + k[src]_h) / sqrt(D)
//   a[h]  = exp(lrelu(aw) @ Waw + baw)
// accumulate acc += a (*) v[src], sa += a ; agg[n] = acc / sa  (single pass, linearity)
__global__ __launch_bounds__(128)
void edge_fused(const unsigned short* __restrict__ kea,
                const unsigned short* __restrict__ qkv,
                const float* __restrict__ Waw, const float* __restrict__ baw,
                const int* __restrict__ rowptr, const int* __restrict__ src_s,
                unsigned short* __restrict__ agg)
{
    __shared__ float awsh[HH];
    __shared__ float WawS[HH * HH];
    __shared__ float bawS[HH];
    const int n = blockIdx.x;
    const int t = threadIdx.x;      // 0..127, 6 features each
    const int d0 = t * 6;
    const int h = t >> 4;           // 16 threads per head
    if (t < HH * HH) WawS[t] = Waw[t];
    if (t < HH) bawS[t] = baw[t];
    const int jlo = rowptr[n], jhi = rowptr[n + 1];
    // q features (dword offset: d0*2 bytes = 12t, 4B-aligned)
    const unsigned int* qr = reinterpret_cast<const unsigned int*>(qkv + (size_t)n * (3 * DD) + d0);
    float q[6];
    b2f2(qr[0], q[0], q[1]); b2f2(qr[1], q[2], q[3]); b2f2(qr[2], q[4], q[5]);
    float acc[6] = {0.f, 0.f, 0.f, 0.f, 0.f, 0.f};
    float sa = 0.f;
    constexpr float rs = 0.03608439182435161f; // 1/sqrt(768)
    __syncthreads();
    for (int j = jlo; j < jhi; j++) {
        int s = src_s[j];
        const unsigned int* ke = reinterpret_cast<const unsigned int*>(kea + (size_t)j * DD + d0);
        const unsigned int* kr = reinterpret_cast<const unsigned int*>(qkv + (size_t)s * (3 * DD) + DD + d0);
        const unsigned int* vr = reinterpret_cast<const unsigned int*>(qkv + (size_t)s * (3 * DD) + 2 * DD + d0);
        float part = 0.f;
        float ka, kb2, va, vb;
#pragma unroll
        for (int c = 0; c < 3; c++) {
            b2f2(ke[c], ka, kb2);
            b2f2(kr[c], va, vb);
            part = fmaf(q[2 * c], ka + va, part);
            part = fmaf(q[2 * c + 1], kb2 + vb, part);
        }
        // reduce over the 16 lanes of this head group
        part += __shfl_xor(part, 1);
        part += __shfl_xor(part, 2);
        part += __shfl_xor(part, 4);
        part += __shfl_xor(part, 8);
        if ((t & 15) == 0) awsh[h] = part;
        __syncthreads();
        float zz = bawS[h];
#pragma unroll
        for (int h2 = 0; h2 < HH; h2++) {
            float aw = awsh[h2] * rs;
            float tt = aw > 0.f ? aw : 0.2f * aw;
            zz = fmaf(tt, WawS[h2 * HH + h], zz);
        }
        float a = expf(zz);
        sa += a;
        float v0, v1;
#pragma unroll
        for (int c = 0; c < 3; c++) {
            b2f2(vr[c], v0, v1);
            acc[2 * c]     = fmaf(a, v0, acc[2 * c]);
            acc[2 * c + 1] = fmaf(a, v1, acc[2 * c + 1]);
        }
        __syncthreads();   // awsh safe to overwrite next edge
    }
    float inv = (sa == 0.f) ? 1.f : 1.f / sa;
    unsigned int* ag = reinterpret_cast<unsigned int*>(agg + (size_t)n * DD + d0);
    ag[0] = packbf(acc[0] * inv, acc[1] * inv);
    ag[1] = packbf(acc[2] * inv, acc[3] * inv);
    ag[2] = packbf(acc[4] * inv, acc[5] * inv);
}

// one wave per node: z = lrelu(g)@Wla2 + bla2 ; la = softmax(z) ; out = x*la0 + h*la1
__global__ __launch_bounds__(256)
void combine_kernel(const unsigned short* __restrict__ g, const float* __restrict__ Wla2,
                    const float* __restrict__ bla2, unsigned short* __restrict__ x16,
                    const unsigned short* __restrict__ h, float* __restrict__ outf, int Nn)
{
    int w = threadIdx.x >> 6;
    int lane = threadIdx.x & 63;
    int n = blockIdx.x * 4 + w;
    if (n >= Nn) return;
    float z0 = 0.f, z1 = 0.f;
#pragma unroll
    for (int p = 0; p < 3; p++) {
        int d = p * 256 + lane * 4;
        const unsigned short* gp = g + (size_t)n * DD + d;
#pragma unroll
        for (int j = 0; j < 4; j++) {
            float gv = b2f(gp[j]);
            float tt = gv > 0.f ? gv : 0.2f * gv;
            z0 = fmaf(tt, Wla2[(d + j) * 2 + 0], z0);
            z1 = fmaf(tt, Wla2[(d + j) * 2 + 1], z1);
        }
    }
#pragma unroll
    for (int off = 32; off > 0; off >>= 1) {
        z0 += __shfl_xor(z0, off);
        z1 += __shfl_xor(z1, off);
    }
    z0 += bla2[0]; z1 += bla2[1];
    float mx = fmaxf(z0, z1);
    float e0v = expf(z0 - mx), e1v = expf(z1 - mx);
    float inv = 1.f / (e0v + e1v);
    float la0 = e0v * inv, la1 = e1v * inv;
#pragma unroll
    for (int p = 0; p < 3; p++) {
        int d = p * 256 + lane * 4;
        unsigned short* xp = x16 + (size_t)n * DD + d;
        const unsigned short* hp = h + (size_t)n * DD + d;
        float o[4];
#pragma unroll
        for (int j = 0; j < 4; j++)
            o[j] = b2f(xp[j]) * la0 + b2f(hp[j]) * la1;
#pragma unroll
        for (int j = 0; j < 4; j++) xp[j] = f2b_rne(o[j]);
        if (outf) {
            float4 ov = make_float4(o[0], o[1], o[2], o[3]);
            *reinterpret_cast<float4*>((float*)outf + (size_t)n * DD + d) = ov;
        }
    }
}

extern "C" void kernel_launch(void* const* d_in, const int* in_sizes, int n_in,
                              void* d_out, int out_size, void* d_ws, size_t ws_size,
                              hipStream_t stream)
{
    const int N = NN, E = EE;
    const float* x_in      = (const float*)d_in[0];
    const float* edge_attr = (const float*)d_in[1];
    const float* Wck = (const float*)d_in[2];
    const float* bck = (const float*)d_in[3];
    const float* Wq  = (const float*)d_in[4];
    const float* bq  = (const float*)d_in[5];
    const float* Wv  = (const float*)d_in[6];
    const float* bv  = (const float*)d_in[7];
    const float* Waw = (const float*)d_in[8];
    const float* baw = (const float*)d_in[9];
    const float* Wc  = (const float*)d_in[10];
    const float* bc  = (const float*)d_in[11];
    const float* Wlx = (const float*)d_in[12];
    const float* blx = (const float*)d_in[13];
    const float* Wla1 = (const float*)d_in[14];
    const float* bla1 = (const float*)d_in[15];
    const float* Wla2 = (const float*)d_in[16];
    const float* bla2 = (const float*)d_in[17];
    const int* eidx = (const int*)d_in[18];
    const int* srcp = eidx;       // edge_index[0]
    const int* dstp = eidx + E;   // edge_index[1]

    const size_t DDDD = (size_t)DD * DD;
    float* p = (float*)d_ws;
    const size_t NB = (size_t)N * DD;
    float* degf  = p; p += N;
    float* wfx32 = p; p += NL * DDDD;
    float* bfbuf = p; p += NL * DD;
    float* bqkvb = p; p += NL * 3 * DD;
    // int region
    int* rowptr = (int*)p;
    int* cursor = rowptr + (N + 1);
    int* perm   = cursor + N;
    int* src_s  = perm + E;
    p += (size_t)(2 * N + 1 + 2 * E + 63) / 64 * 64;
    // bf16 regions (counted in floats = elems/2)
    unsigned short* xb16  = (unsigned short*)p; p += NB / 2;
    unsigned short* hb16  = (unsigned short*)p; p += NB / 2;
    unsigned short* agg16 = (unsigned short*)p; p += NB / 2;
    unsigned short* qkv16 = (unsigned short*)p; p += 3 * NB / 2;   // [N][2304]
    unsigned short* ea16  = (unsigned short*)p; p += (size_t)E * DD / 2;
    unsigned short* kea16 = (unsigned short*)p; p += (size_t)E * DD / 2;
    unsigned short* gb16  = qkv16;                 // reuse after edge_fused
    // weights (all NL layers)
    unsigned short* wqkvt  = (unsigned short*)p; p += NL * 3 * DDDD / 2; // [l][2304][768]
    unsigned short* wcktopt= (unsigned short*)p; p += NL * DDDD / 2;
    unsigned short* wct    = (unsigned short*)p; p += NL * DDDD / 2;
    unsigned short* wla1tt = (unsigned short*)p; p += NL * DDDD / 2;
    unsigned short* wst3   = (unsigned short*)p; p += NL * 2 * DDDD / 2; // [l][768][1536]
    unsigned short* wlx16  = (unsigned short*)p; p += NL * DDDD / 2;

    // ================= setup (once) =================
    hipMemsetAsync(cursor, 0, N * sizeof(int), stream);
    deg_kernel<<<(E + 255) / 256, 256, 0, stream>>>(dstp, cursor);
    scan_kernel<<<1, 256, 0, stream>>>(cursor, rowptr, cursor);
    fill_perm<<<(E + 255) / 256, 256, 0, stream>>>(srcp, dstp, cursor, perm, src_s);
    degf_kernel<<<(N + 255) / 256, 256, 0, stream>>>(rowptr, degf);
    f2b_gather<<<(E * 96 + 255) / 256, 256, 0, stream>>>(edge_attr, perm, ea16);
    f2b_kernel<<<(N * 96 + 255) / 256, 256, 0, stream>>>(x_in, xb16, N * 96);

    // ---- batched weight prep (z = layer) ----
    dim3 gt3(DD / 32, DD / 32, NL);
    transpose_w<<<gt3, 256, 0, stream>>>(Wq, wqkvt, DD, DD, 0, DDDD, 3 * DDDD);
    transpose_w<<<gt3, 256, 0, stream>>>(Wck + DDDD, wqkvt + DDDD, DD, DD, 0, 2 * DDDD, 3 * DDDD);
    transpose_w<<<gt3, 256, 0, stream>>>(Wv, wqkvt + 2 * DDDD, DD, DD, 0, DDDD, 3 * DDDD);
    transpose_w<<<gt3, 256, 0, stream>>>(Wck, wcktopt, DD, DD, 0, 2 * DDDD, DDDD);
    transpose_w<<<gt3, 256, 0, stream>>>(Wc, wct, DD, DD, 0, DDDD, DDDD);
    transpose_w<<<gt3, 256, 0, stream>>>(Wla1, wla1tt, DD, DD, 0, 2 * DDDD, DDDD);
    transpose_w<<<gt3, 256, 0, stream>>>(Wla1 + DDDD, wst3, DD, 2 * DD, DD, 2 * DDDD, 2 * DDDD);
    f2b_kernel<<<(NL * DD * 96 + 255) / 256, 256, 0, stream>>>(Wlx, wlx16, NL * DD * 96);
    // wfx[l] = Wlx[l] @ Wla1_top[l]  (batched z=NL)
    gemm_mfma<<<dim3(6, 3, NL), 512, 0, stream>>>(wlx16, nullptr, wla1tt, nullptr, nullptr,
                                                  wfx32, nullptr, DD, DD, DD,
                                                  DDDD, DDDD, DDDD);
    transpose_w<<<gt3, 256, 0, stream>>>(wfx32, wst3, DD, 2 * DD, 0, DDDD, 2 * DDDD);
    biasf_kernel<<<dim3(3, NL), 256, 0, stream>>>(blx, Wla1, bla1, bfbuf);
    biasqkv_kernel<<<dim3(9, NL), 256, 0, stream>>>(bq, bv, bqkvb);

    // ================= layer loop =================
    for (int l = 0; l < NL; l++) {
        const float* bck_l = bck + (size_t)l * DD;
        const float* Waw_l = Waw + (size_t)l * HH * HH;
        const float* baw_l = baw + (size_t)l * HH;
        const float* bc_l  = bc  + (size_t)l * DD;
        const float* Wla2_l = Wla2 + (size_t)l * DD * 2;
        const float* bla2_l = bla2 + (size_t)l * 2;

        // ---- qkv node GEMM [N][2304] ----
        gemm_mfma<<<dim3(18, (N + 255) / 256), 512, 0, stream>>>(
            xb16, nullptr, wqkvt + (size_t)l * 3 * DDDD, bqkvb + (size_t)l * 3 * DD,
            nullptr, nullptr, qkv16, N, DD, 3 * DD, 0, 0, 0);
        // ---- kea edge GEMM [E][768] ----
        gemm_mfma<<<dim3(6, (E + 255) / 256), 512, 0, stream>>>(
            ea16, nullptr, wcktopt + (size_t)l * DDDD, bck_l,
            nullptr, nullptr, kea16, E, DD, DD, 0, 0, 0);
        // ---- fused attention + aggregation (single pass) ----
        edge_fused<<<N, 128, 0, stream>>>(kea16, qkv16, Waw_l, baw_l, rowptr, src_s, agg16);
        // ---- h = agg @ Wc + deg*bc (bf16 out only) ----
        gemm_mfma<<<dim3(6, (N + 255) / 256), 512, 0, stream>>>(
            agg16, nullptr, wct + (size_t)l * DDDD, bc_l,
            degf, nullptr, hb16, N, DD, DD, 0, 0, 0);
        // ---- g = x@Wfx + h@Wla1_bot + bf ----
        gemm_mfma<<<dim3(6, (N + 255) / 256), 512, 0, stream>>>(
            xb16, hb16, wst3 + (size_t)l * 2 * DDDD, bfbuf + (size_t)l * DD,
            nullptr, nullptr, gb16, N, 2 * DD, DD, 0, 0, 0);
        // ---- gated combine ----
        combine_kernel<<<(N + 3) / 4, 256, 0, stream>>>(
            gb16, Wla2_l, bla2_l, xb16, hb16,
            (l == NL - 1) ? (float*)d_out : nullptr, N);
    }
}